// Round 10
// baseline (274.521 us; speedup 1.0000x reference)
//
#include <hip/hip_runtime.h>

// CompressedLinear: out = x[8192,4096] @ (W_int8[4096,4096]*scale)^T + bias.
// Round 10: 1-barrier/K-tile pipelined schedule. Seg t (buf c=t&1):
//   [BAR]  (publishes buf c = tile t; staged last seg, vmcnt(0)'d)
//   stage A+B (1-c <- t+1)      // 8 gloads, other buffer ONLY -> race-free
//   G1: ldB(8) + ldA01(8)       // current tile reads
//   G2: ldA23(8)                // issued BEFORE C0 -> drains under C0's MFMAs
//   C0: mt01 x nt01 (16 MFMA)   // compiler partial-lgkm waits G1 only
//   C1: mt23 x nt01 (16 MFMA)   // waits G2 (already drained)
//   WAITV0 (free: stages issued ~3000 cyc ago)  [next BAR]
// Ledger safety: reads of buf c all execute before the wave's own lgkm-waited
// MFMAs -> before BAR; stages into buf c happen only in the NEXT segment
// (after that BAR). Stages target only buf 1-c this segment. No region overlap.
// Geometry/swizzle identical to rounds 6-9 (proven zero-conflict, absmax OK).

#define BM 256
#define BN 256
#define BKB 128                 // K-bytes per tile = 128 int8

constexpr int Mdim = 8192;
constexpr int Ndim = 4096;
constexpr int Kdim = 4096;
constexpr int KT = Kdim / BKB;  // 32

typedef __attribute__((ext_vector_type(4)))  int   int32x4;
typedef __attribute__((ext_vector_type(16))) int   int32x16;
typedef __attribute__((ext_vector_type(8)))  short short8;
typedef __attribute__((ext_vector_type(4)))  float f32x4;
typedef unsigned short ushort_t;

__device__ __forceinline__ unsigned short f2bf(float f) {
    union { float f; unsigned u; } v; v.f = f;
    unsigned r = v.u + 0x7FFFu + ((v.u >> 16) & 1u);
    return (unsigned short)(r >> 16);
}

__device__ __forceinline__ void gload_lds16(const void* g, void* l) {
    __builtin_amdgcn_global_load_lds(
        (const __attribute__((address_space(1))) void*)g,
        (__attribute__((address_space(3))) void*)l, 16, 0, 0);
}

#define BARRIER() __builtin_amdgcn_s_barrier()
#define WAITV0()  asm volatile("s_waitcnt vmcnt(0)" ::: "memory")

// ---------------- prep kernels ----------------------------------------------

__global__ __launch_bounds__(256)
void quant_x_rowwise(const float* __restrict__ x, char* __restrict__ xq,
                     float* __restrict__ sx) {
    const int row = blockIdx.x;
    const float4* xr = reinterpret_cast<const float4*>(x + (size_t)row * Kdim);
    const int tid = threadIdx.x;
    float4 v[4];
    float am = 0.f;
    #pragma unroll
    for (int j = 0; j < 4; ++j) {
        v[j] = xr[tid + 256 * j];
        am = fmaxf(am, fmaxf(fmaxf(fabsf(v[j].x), fabsf(v[j].y)),
                             fmaxf(fabsf(v[j].z), fabsf(v[j].w))));
    }
    #pragma unroll
    for (int off = 32; off; off >>= 1)
        am = fmaxf(am, __shfl_xor(am, off, 64));
    __shared__ float red[4];
    if ((tid & 63) == 0) red[tid >> 6] = am;
    __syncthreads();
    am = fmaxf(fmaxf(red[0], red[1]), fmaxf(red[2], red[3]));
    am = fmaxf(am, 1e-30f);
    if (tid == 0) sx[row] = am / 127.f;
    const float inv = 127.f / am;
    int* outw = reinterpret_cast<int*>(xq + (size_t)row * Kdim);
    #pragma unroll
    for (int j = 0; j < 4; ++j) {
        const int q0 = (int)rintf(v[j].x * inv) & 255;
        const int q1 = (int)rintf(v[j].y * inv) & 255;
        const int q2 = (int)rintf(v[j].z * inv) & 255;
        const int q3 = (int)rintf(v[j].w * inv) & 255;
        outw[tid + 256 * j] = q0 | (q1 << 8) | (q2 << 16) | (q3 << 24);
    }
}

__global__ __launch_bounds__(256)
void pack_w_int8(const int* __restrict__ w, char* __restrict__ wq, int n4) {
    int idx = blockIdx.x * blockDim.x + threadIdx.x;
    const int stride = gridDim.x * blockDim.x;
    int* out = reinterpret_cast<int*>(wq);
    for (int i = idx; i < n4; i += stride) {
        const int4 a = reinterpret_cast<const int4*>(w)[i];
        out[i] = (a.x & 255) | ((a.y & 255) << 8) |
                 ((a.z & 255) << 16) | ((a.w & 255) << 24);
    }
}

// ---------------- 256x256 1-barrier/K-tile int8 GEMM ------------------------

__global__ __launch_bounds__(512, 2)
void gemm_i8_pipe(const char* __restrict__ A,   // [M][K] int8
                  const char* __restrict__ B,   // [N][K] int8
                  const float* __restrict__ scale,
                  const float* __restrict__ bias,
                  const float* __restrict__ sx,
                  float* __restrict__ Out)
{
    // [buf][region: A=0, B=1][32 KiB] = 128 KiB
    __shared__ __align__(16) char smem[2][2][32768];

    const int tid = threadIdx.x;
    int bid = blockIdx.x;
    bid = (bid & 7) * 64 + (bid >> 3);          // bijective XCD swizzle (512%8==0)
    const int tn = bid & 15;                    // N/BN = 16
    const int tm = bid >> 4;                    // M/BM = 32
    const int brow = tm * BM;
    const int bcol = tn * BN;

    const int lane = tid & 63;
    const int w    = tid >> 6;                  // 8 waves
    const int wr   = w >> 2;                    // 2 M-waves
    const int wc   = w & 3;                     // 4 N-waves
    const int r32  = lane & 31;
    const int h    = lane >> 5;                 // k-group
    const size_t K1 = (size_t)Kdim;

    // staging: rows w*8+(lane>>3) + 64*i, i=0..3 (covers 0..255)
    // two-level swizzle nibble = (l&7)^(row&7)^((row>>3)&3) = (l&7)^(lane>>3)^(w&3)
    const int swzb = ((lane & 7) ^ (lane >> 3) ^ (w & 3)) << 4;
    const char* aStageSrc = A + (size_t)(brow + w * 8 + (lane >> 3)) * K1 + swzb;
    const char* bStageSrc = B + (size_t)(bcol + w * 8 + (lane >> 3)) * K1 + swzb;

    auto stageA = [&](int bufb, int tt) {       // 4 gloads: full 256-row A tile
        const char* s = aStageSrc + (size_t)tt * BKB;
        char* d = &smem[bufb][0][w * 1024];
        #pragma unroll
        for (int i = 0; i < 4; ++i)
            gload_lds16(s + (size_t)(64 * i) * K1, d + i * 8192);
    };
    auto stageB = [&](int bufb, int tt) {
        const char* s = bStageSrc + (size_t)tt * BKB;
        char* d = &smem[bufb][1][w * 1024];
        #pragma unroll
        for (int i = 0; i < 4; ++i)
            gload_lds16(s + (size_t)(64 * i) * K1, d + i * 8192);
    };

    // ds_read bases (128 B rows; swizzle identical to rounds 6-9)
    const char* aBase[2] = { &smem[0][0][0] + r32 * 128 + wr * 16384,
                             &smem[1][0][0] + r32 * 128 + wr * 16384 };
    const char* bBase[2] = { &smem[0][1][0] + (wc * 64 + r32) * 128,
                             &smem[1][1][0] + (wc * 64 + r32) * 128 };
    const int frx = ((r32 & 7) ^ (r32 >> 3)) << 4;
    int colb[4];
    #pragma unroll
    for (int ks = 0; ks < 4; ++ks) colb[ks] = (ks * 32 + h * 16) ^ frx;

    int32x16 acc[4][2] = {};            // [m-tile][n-tile]
    int32x4 af01[2][4], af23[2][4], bf[2][4];

    auto ldB = [&](const char* base) {
        #pragma unroll
        for (int nt = 0; nt < 2; ++nt)
            #pragma unroll
            for (int ks = 0; ks < 4; ++ks)
                bf[nt][ks] = *reinterpret_cast<const int32x4*>(base + nt * 4096 + colb[ks]);
    };
    auto ldA01 = [&](const char* base) {
        #pragma unroll
        for (int mt = 0; mt < 2; ++mt)
            #pragma unroll
            for (int ks = 0; ks < 4; ++ks)
                af01[mt][ks] = *reinterpret_cast<const int32x4*>(base + mt * 4096 + colb[ks]);
    };
    auto ldA23 = [&](const char* base) {
        #pragma unroll
        for (int mt = 0; mt < 2; ++mt)
            #pragma unroll
            for (int ks = 0; ks < 4; ++ks)
                af23[mt][ks] = *reinterpret_cast<const int32x4*>(base + (2 + mt) * 4096 + colb[ks]);
    };

    // ---- prologue: stage t0 -> buf0, full drain
    stageA(0, 0); stageB(0, 0);
    WAITV0();
    BARRIER();

    for (int t = 0; t < KT; ++t) {
        const int c = t & 1;
        // stage next tile into the OTHER buffer (issues early, lands under MFMA)
        if (t + 1 < KT) { stageA(1 - c, t + 1); stageB(1 - c, t + 1); }

        // G1: reads consumed by C0
        ldB(bBase[c]);
        ldA01(aBase[c]);
        // G2: reads consumed by C1 — issued before C0 so drain hides under C0
        ldA23(aBase[c]);

        // C0: mt 0-1 x nt 0-1 (compiler partial-lgkm waits G1 only)
        __builtin_amdgcn_s_setprio(1);
        #pragma unroll
        for (int mt = 0; mt < 2; ++mt)
            #pragma unroll
            for (int nt = 0; nt < 2; ++nt)
                #pragma unroll
                for (int ks = 0; ks < 4; ++ks)
                    acc[mt][nt] = __builtin_amdgcn_mfma_i32_32x32x32_i8(
                        af01[mt][ks], bf[nt][ks], acc[mt][nt], 0, 0, 0);
        __builtin_amdgcn_s_setprio(0);

        // C1: mt 2-3 x nt 0-1
        __builtin_amdgcn_s_setprio(1);
        #pragma unroll
        for (int mt = 0; mt < 2; ++mt)
            #pragma unroll
            for (int nt = 0; nt < 2; ++nt)
                #pragma unroll
                for (int ks = 0; ks < 4; ++ks)
                    acc[2 + mt][nt] = __builtin_amdgcn_mfma_i32_32x32x32_i8(
                        af23[mt][ks], bf[nt][ks], acc[2 + mt][nt], 0, 0, 0);
        __builtin_amdgcn_s_setprio(0);

        WAITV0();      // stages issued ~3000 cyc ago: effectively free
        BARRIER();
    }

    // epilogue: out = acc * scale[col] * scale_x[row] + bias[col]
    // C/D (32x32): col=lane&31, row=(reg&3)+8*(reg>>2)+4*(lane>>5)
    #pragma unroll
    for (int nt = 0; nt < 2; ++nt) {
        const int col = bcol + wc * 64 + nt * 32 + r32;
        const float sc = scale[col];
        const float bi = bias[col];
        #pragma unroll
        for (int mt = 0; mt < 4; ++mt) {
            const int rb = brow + wr * 128 + mt * 32 + 4 * h;
            #pragma unroll
            for (int q = 0; q < 4; ++q) {
                const int r4 = rb + 8 * q;
                #pragma unroll
                for (int r = 0; r < 4; ++r) {
                    const float sxr = sx[r4 + r];
                    Out[(size_t)(r4 + r) * Ndim + col] =
                        (float)acc[mt][nt][q * 4 + r] * (sc * sxr) + bi;
                }
            }
        }
    }
}

// ---------------- fallback (round-1 kernel) if ws too small -----------------

__device__ __forceinline__ int swz_fb(int row, int colbyte) {
    return row * 128 + (colbyte ^ ((row & 7) << 4));
}

__global__ __launch_bounds__(256)
void compressed_linear_fb(const float* __restrict__ X,
                          const int*   __restrict__ W,
                          const float* __restrict__ scale,
                          const float* __restrict__ bias,
                          float* __restrict__ Out)
{
    __shared__ __align__(16) ushort_t lA[128 * 64];
    __shared__ __align__(16) ushort_t lB[128 * 64];
    const int tid = threadIdx.x;
    const int bid = blockIdx.x;
    const int tn = bid & 31, tm = bid >> 5;
    const int brow = tm * 128, bcol = tn * 128;
    const int r0 = tid >> 3, c0 = tid & 7;
    float4 aPre[4][2]; int4 bPre[4][2];
    const int lane = tid & 63, w = tid >> 6;
    const int wr = w >> 1, wc = w & 1, fr = lane & 15, fq = lane >> 4;
    f32x4 acc[4][4] = {};

    auto loadTiles = [&](int t) {
        const int k0 = t * 64;
        #pragma unroll
        for (int i = 0; i < 4; i++) {
            const int row = r0 + 32 * i;
            const float4* pa = reinterpret_cast<const float4*>(X + (size_t)(brow + row) * Kdim + k0 + c0 * 8);
            aPre[i][0] = pa[0]; aPre[i][1] = pa[1];
            const int4* pb = reinterpret_cast<const int4*>(W + (size_t)(bcol + row) * Kdim + k0 + c0 * 8);
            bPre[i][0] = pb[0]; bPre[i][1] = pb[1];
        }
    };
    auto writeLDS = [&]() {
        #pragma unroll
        for (int i = 0; i < 4; i++) {
            const int row = r0 + 32 * i;
            const int off = swz_fb(row, c0 * 16);
            short8 va, vb;
            va[0] = (short)f2bf(aPre[i][0].x); va[1] = (short)f2bf(aPre[i][0].y);
            va[2] = (short)f2bf(aPre[i][0].z); va[3] = (short)f2bf(aPre[i][0].w);
            va[4] = (short)f2bf(aPre[i][1].x); va[5] = (short)f2bf(aPre[i][1].y);
            va[6] = (short)f2bf(aPre[i][1].z); va[7] = (short)f2bf(aPre[i][1].w);
            vb[0] = (short)f2bf((float)bPre[i][0].x); vb[1] = (short)f2bf((float)bPre[i][0].y);
            vb[2] = (short)f2bf((float)bPre[i][0].z); vb[3] = (short)f2bf((float)bPre[i][0].w);
            vb[4] = (short)f2bf((float)bPre[i][1].x); vb[5] = (short)f2bf((float)bPre[i][1].y);
            vb[6] = (short)f2bf((float)bPre[i][1].z); vb[7] = (short)f2bf((float)bPre[i][1].w);
            *reinterpret_cast<short8*>(reinterpret_cast<char*>(lA) + off) = va;
            *reinterpret_cast<short8*>(reinterpret_cast<char*>(lB) + off) = vb;
        }
    };

    loadTiles(0);
    for (int t = 0; t < Kdim / 64; t++) {
        writeLDS();
        __syncthreads();
        if (t + 1 < Kdim / 64) loadTiles(t + 1);
        #pragma unroll
        for (int kk = 0; kk < 2; kk++) {
            short8 afv[4], bfv[4];
            const int cb = kk * 64 + fq * 16;
            #pragma unroll
            for (int m = 0; m < 4; m++) {
                const int row = wr * 64 + m * 16 + fr;
                afv[m] = *reinterpret_cast<const short8*>(reinterpret_cast<const char*>(lA) + swz_fb(row, cb));
            }
            #pragma unroll
            for (int n = 0; n < 4; n++) {
                const int row = wc * 64 + n * 16 + fr;
                bfv[n] = *reinterpret_cast<const short8*>(reinterpret_cast<const char*>(lB) + swz_fb(row, cb));
            }
            #pragma unroll
            for (int m = 0; m < 4; m++)
                #pragma unroll
                for (int n = 0; n < 4; n++)
                    acc[m][n] = __builtin_amdgcn_mfma_f32_16x16x32_bf16(afv[m], bfv[n], acc[m][n], 0, 0, 0);
        }
        __syncthreads();
    }
    #pragma unroll
    for (int n = 0; n < 4; n++) {
        const int col = bcol + wc * 64 + n * 16 + fr;
        const float sc = scale[col];
        const float bi = bias[col];
        #pragma unroll
        for (int m = 0; m < 4; m++) {
            const int rbase = brow + wr * 64 + m * 16 + fq * 4;
            #pragma unroll
            for (int j = 0; j < 4; j++)
                Out[(size_t)(rbase + j) * Ndim + col] = acc[m][n][j] * sc + bi;
        }
    }
}

// ---------------------------------------------------------------------------

extern "C" void kernel_launch(void* const* d_in, const int* in_sizes, int n_in,
                              void* d_out, int out_size, void* d_ws, size_t ws_size,
                              hipStream_t stream) {
    const float* x     = (const float*)d_in[0];
    const int*   w8    = (const int*)d_in[1];
    const float* scale = (const float*)d_in[2];
    const float* bias  = (const float*)d_in[3];
    float* out = (float*)d_out;

    const size_t xq_bytes = (size_t)Mdim * Kdim;        // 32 MiB
    const size_t wq_bytes = (size_t)Ndim * Kdim;        // 16 MiB
    const size_t sx_bytes = (size_t)Mdim * sizeof(float);

    if (ws_size >= xq_bytes + wq_bytes + sx_bytes) {
        char*  xq = (char*)d_ws;
        char*  wq = (char*)d_ws + xq_bytes;
        float* sx = (float*)((char*)d_ws + xq_bytes + wq_bytes);
        quant_x_rowwise<<<Mdim, 256, 0, stream>>>(x, xq, sx);
        pack_w_int8<<<2048, 256, 0, stream>>>(w8, wq, (Ndim * Kdim) / 4);
        dim3 grid((Mdim / BM) * (Ndim / BN));           // 32*16 = 512 blocks
        gemm_i8_pipe<<<grid, dim3(512), 0, stream>>>(xq, wq, scale, bias, sx, out);
    } else {
        dim3 grid((Mdim / 128) * (Ndim / 128));         // 2048 blocks
        compressed_linear_fb<<<grid, dim3(256), 0, stream>>>(x, w8, scale, bias, out);
    }
}

// Round 11
// 240.181 us; speedup vs baseline: 1.1430x; 1.1430x over previous
//
#include <hip/hip_runtime.h>

// CompressedLinear: out = x[8192,4096] @ (W_int8[4096,4096]*scale)^T + bias.
// Round 11: move B out of LDS. pack_w now emits W in MFMA-fragment order so
// the GEMM loads B global->register fully coalesced (1KB/instr); LDS carries
// A only (2x32KiB dbuf). Per-CU per-K-tile: LDS 128 reads+A-DMA ~1800 cyc <
// MFMA 2340 -> MFMA is the pole. Round-10 lessons applied: loadB issued
// BEFORE stageA (auto vmcnt(4) for bf leaves stages in flight), issue
// clusters pinned with sched_barrier(0) so the compiler can't sink them.
//
// B packed layout (produced by pack_w_frag, consumed by loadB — same formula):
//   chunk(nb,t,ks) at ((nb*KT + t)*4 + ks)*1024, byte lane*16+j =
//   W[col = nb*32 + (lane&31)][k = t*128 + ks*32 + (lane>>5)*16 + j]
//   which is exactly the mfma_i32_32x32x32_i8 B fragment (col=lane&31,
//   k0=(lane>>5)*16), nb = 32-col block.
//
// Segment t (buf c=t&1): loadB(t)->bf | stageA(1-c,t+1) | SCHED_FENCE |
//   [buf c published by prev BAR] ldA01,ldA23 | C0 (auto vmcnt(4)+lgkm) | C1 |
//   WAITV0 (4 stages, issued ~2700cyc ago) | BARRIER.
// Race ledger: stage into buf(1-c) = buffer read in segment t-1, whose MFMAs
// consumed the reads before the prev BAR. Reads of buf c staged in seg t-1,
// WAITV0+BAR'd. Tail: t=KT-1 stages nothing; WAITV0 trivially free.

#define BM 256
#define BN 256
#define BKB 128                 // K-bytes per tile = 128 int8

constexpr int Mdim = 8192;
constexpr int Ndim = 4096;
constexpr int Kdim = 4096;
constexpr int KT = Kdim / BKB;  // 32

typedef __attribute__((ext_vector_type(4)))  int   int32x4;
typedef __attribute__((ext_vector_type(16))) int   int32x16;
typedef __attribute__((ext_vector_type(8)))  short short8;
typedef __attribute__((ext_vector_type(4)))  float f32x4;
typedef unsigned short ushort_t;

__device__ __forceinline__ unsigned short f2bf(float f) {
    union { float f; unsigned u; } v; v.f = f;
    unsigned r = v.u + 0x7FFFu + ((v.u >> 16) & 1u);
    return (unsigned short)(r >> 16);
}

__device__ __forceinline__ void gload_lds16(const void* g, void* l) {
    __builtin_amdgcn_global_load_lds(
        (const __attribute__((address_space(1))) void*)g,
        (__attribute__((address_space(3))) void*)l, 16, 0, 0);
}

#define BARRIER() __builtin_amdgcn_s_barrier()
#define WAITV0()  asm volatile("s_waitcnt vmcnt(0)" ::: "memory")
#define SCHED_FENCE() __builtin_amdgcn_sched_barrier(0)

// ---------------- prep kernels ----------------------------------------------

__global__ __launch_bounds__(256)
void quant_x_rowwise(const float* __restrict__ x, char* __restrict__ xq,
                     float* __restrict__ sx) {
    const int row = blockIdx.x;
    const float4* xr = reinterpret_cast<const float4*>(x + (size_t)row * Kdim);
    const int tid = threadIdx.x;
    float4 v[4];
    float am = 0.f;
    #pragma unroll
    for (int j = 0; j < 4; ++j) {
        v[j] = xr[tid + 256 * j];
        am = fmaxf(am, fmaxf(fmaxf(fabsf(v[j].x), fabsf(v[j].y)),
                             fmaxf(fabsf(v[j].z), fabsf(v[j].w))));
    }
    #pragma unroll
    for (int off = 32; off; off >>= 1)
        am = fmaxf(am, __shfl_xor(am, off, 64));
    __shared__ float red[4];
    if ((tid & 63) == 0) red[tid >> 6] = am;
    __syncthreads();
    am = fmaxf(fmaxf(red[0], red[1]), fmaxf(red[2], red[3]));
    am = fmaxf(am, 1e-30f);
    if (tid == 0) sx[row] = am / 127.f;
    const float inv = 127.f / am;
    int* outw = reinterpret_cast<int*>(xq + (size_t)row * Kdim);
    #pragma unroll
    for (int j = 0; j < 4; ++j) {
        const int q0 = (int)rintf(v[j].x * inv) & 255;
        const int q1 = (int)rintf(v[j].y * inv) & 255;
        const int q2 = (int)rintf(v[j].z * inv) & 255;
        const int q3 = (int)rintf(v[j].w * inv) & 255;
        outw[tid + 256 * j] = q0 | (q1 << 8) | (q2 << 16) | (q3 << 24);
    }
}

// W int32 -> int8, rewritten into MFMA-fragment order (see header comment)
__global__ __launch_bounds__(256)
void pack_w_frag(const int* __restrict__ w, char* __restrict__ bp) {
    const int g = blockIdx.x * 256 + threadIdx.x;   // 16B granule id, 1,048,576 total
    const int l  = g & 63;
    const int ks = (g >> 6) & 3;
    const int t  = (g >> 8) & 31;
    const int nb = g >> 13;                         // [0,128)
    const int col = nb * 32 + (l & 31);
    const int kb  = t * 128 + ks * 32 + (l >> 5) * 16;
    const int4* src = reinterpret_cast<const int4*>(w + (size_t)col * Kdim + kb);
    int4 a = src[0], b = src[1], c = src[2], d = src[3];
    int4 o;
    o.x = (a.x & 255) | ((a.y & 255) << 8) | ((a.z & 255) << 16) | ((a.w & 255) << 24);
    o.y = (b.x & 255) | ((b.y & 255) << 8) | ((b.z & 255) << 16) | ((b.w & 255) << 24);
    o.z = (c.x & 255) | ((c.y & 255) << 8) | ((c.z & 255) << 16) | ((c.w & 255) << 24);
    o.w = (d.x & 255) | ((d.y & 255) << 8) | ((d.z & 255) << 16) | ((d.w & 255) << 24);
    reinterpret_cast<int4*>(bp)[g] = o;
}

// ---------------- 256x256 int8 GEMM, A-in-LDS / B-in-registers --------------

__global__ __launch_bounds__(512, 2)
void gemm_i8_breg(const char* __restrict__ A,    // [M][K] int8 (xq)
                  const char* __restrict__ Bp,   // packed W fragments
                  const float* __restrict__ scale,
                  const float* __restrict__ bias,
                  const float* __restrict__ sx,
                  float* __restrict__ Out)
{
    // A only: [buf][256 rows x 128 B] = 64 KiB
    __shared__ __align__(16) char smem[2][32768];

    const int tid = threadIdx.x;
    int bid = blockIdx.x;
    bid = (bid & 7) * 64 + (bid >> 3);          // bijective XCD swizzle (512%8==0)
    const int tn = bid & 15;                    // N/BN = 16
    const int tm = bid >> 4;                    // M/BM = 32
    const int brow = tm * BM;
    const int bcol = tn * BN;

    const int lane = tid & 63;
    const int w    = tid >> 6;                  // 8 waves
    const int wr   = w >> 2;                    // 2 M-waves
    const int wc   = w & 3;                     // 4 N-waves
    const int r32  = lane & 31;
    const size_t K1 = (size_t)Kdim;

    // ---- A staging (two-level swizzle, proven zero-conflict r6-r10) ----
    const int swzb = ((lane & 7) ^ (lane >> 3) ^ (w & 3)) << 4;
    const char* aStageSrc = A + (size_t)(brow + w * 8 + (lane >> 3)) * K1 + swzb;

    auto stageA = [&](int bufb, int tt) {       // 4 gloads: full 256-row A tile
        const char* s = aStageSrc + (size_t)tt * BKB;
        char* d = &smem[bufb][w * 1024];
        #pragma unroll
        for (int i = 0; i < 4; ++i)
            gload_lds16(s + (size_t)(64 * i) * K1, d + i * 8192);
    };

    // ---- A ds_read addressing ----
    const char* aBase[2] = { &smem[0][0] + wr * 16384 + r32 * 128,
                             &smem[1][0] + wr * 16384 + r32 * 128 };
    const int frx = ((r32 & 7) ^ (r32 >> 3)) << 4;
    int colb[4];
    #pragma unroll
    for (int ks = 0; ks < 4; ++ks) colb[ks] = (ks * 32 + (lane >> 5) * 16) ^ frx;

    // ---- B direct-load addressing (packed fragments; coalesced 1KB/instr) --
    // nb = tn*8 + wc*2 + nt ; chunk(nb,t,ks) = ((nb*KT + t)*4 + ks)*1024
    const char* bpBase = Bp + ((size_t)(tn * 8 + wc * 2) * KT) * 4096 + lane * 16;

    int32x16 acc[4][2] = {};            // [m-tile][n-tile]
    int32x4 af01[2][4], af23[2][4], bf[2][4];

    auto loadB = [&](int t) {
        #pragma unroll
        for (int nt = 0; nt < 2; ++nt)
            #pragma unroll
            for (int ks = 0; ks < 4; ++ks)
                bf[nt][ks] = *reinterpret_cast<const int32x4*>(
                    bpBase + (((size_t)nt * KT + t) * 4 + ks) * 1024);
    };
    auto ldA01 = [&](const char* base) {
        #pragma unroll
        for (int mt = 0; mt < 2; ++mt)
            #pragma unroll
            for (int ks = 0; ks < 4; ++ks)
                af01[mt][ks] = *reinterpret_cast<const int32x4*>(base + mt * 4096 + colb[ks]);
    };
    auto ldA23 = [&](const char* base) {
        #pragma unroll
        for (int mt = 0; mt < 2; ++mt)
            #pragma unroll
            for (int ks = 0; ks < 4; ++ks)
                af23[mt][ks] = *reinterpret_cast<const int32x4*>(base + (2 + mt) * 4096 + colb[ks]);
    };

    // ---- prologue: stage t0 -> buf0, drain, publish
    stageA(0, 0);
    WAITV0();
    BARRIER();

    for (int t = 0; t < KT; ++t) {
        const int c = t & 1;

        // B first (so auto-wait for bf = vmcnt(4), stages stay in flight),
        // then next-tile A stage; pin both before anything below.
        loadB(t);
        if (t + 1 < KT) stageA(1 - c, t + 1);
        SCHED_FENCE();

        // current-tile A reads (buf c published by previous barrier)
        ldA01(aBase[c]);
        ldA23(aBase[c]);

        // C0: mt 0-1 (compiler waits vmcnt for bf + partial lgkm for af01;
        // af23 reads drain underneath)
        __builtin_amdgcn_s_setprio(1);
        #pragma unroll
        for (int mt = 0; mt < 2; ++mt)
            #pragma unroll
            for (int nt = 0; nt < 2; ++nt)
                #pragma unroll
                for (int ks = 0; ks < 4; ++ks)
                    acc[mt][nt] = __builtin_amdgcn_mfma_i32_32x32x32_i8(
                        af01[mt][ks], bf[nt][ks], acc[mt][nt], 0, 0, 0);
        __builtin_amdgcn_s_setprio(0);

        // C1: mt 2-3
        __builtin_amdgcn_s_setprio(1);
        #pragma unroll
        for (int mt = 0; mt < 2; ++mt)
            #pragma unroll
            for (int nt = 0; nt < 2; ++nt)
                #pragma unroll
                for (int ks = 0; ks < 4; ++ks)
                    acc[2 + mt][nt] = __builtin_amdgcn_mfma_i32_32x32x32_i8(
                        af23[mt][ks], bf[nt][ks], acc[2 + mt][nt], 0, 0, 0);
        __builtin_amdgcn_s_setprio(0);

        WAITV0();      // 4 stage gloads, issued ~2700 cyc ago: free
        BARRIER();     // publish buf 1-c for next segment
    }

    // epilogue: out = acc * scale[col] * scale_x[row] + bias[col]
    // C/D (32x32): col=lane&31, row=(reg&3)+8*(reg>>2)+4*(lane>>5)
    const int h = lane >> 5;
    #pragma unroll
    for (int nt = 0; nt < 2; ++nt) {
        const int col = bcol + wc * 64 + nt * 32 + r32;
        const float sc = scale[col];
        const float bi = bias[col];
        #pragma unroll
        for (int mt = 0; mt < 4; ++mt) {
            const int rb = brow + wr * 128 + mt * 32 + 4 * h;
            #pragma unroll
            for (int q = 0; q < 4; ++q) {
                const int r4 = rb + 8 * q;
                #pragma unroll
                for (int r = 0; r < 4; ++r) {
                    const float sxr = sx[r4 + r];
                    Out[(size_t)(r4 + r) * Ndim + col] =
                        (float)acc[mt][nt][q * 4 + r] * (sc * sxr) + bi;
                }
            }
        }
    }
}

// ---------------- fallback (round-1 kernel) if ws too small -----------------

__device__ __forceinline__ int swz_fb(int row, int colbyte) {
    return row * 128 + (colbyte ^ ((row & 7) << 4));
}

__global__ __launch_bounds__(256)
void compressed_linear_fb(const float* __restrict__ X,
                          const int*   __restrict__ W,
                          const float* __restrict__ scale,
                          const float* __restrict__ bias,
                          float* __restrict__ Out)
{
    __shared__ __align__(16) ushort_t lA[128 * 64];
    __shared__ __align__(16) ushort_t lB[128 * 64];
    const int tid = threadIdx.x;
    const int bid = blockIdx.x;
    const int tn = bid & 31, tm = bid >> 5;
    const int brow = tm * 128, bcol = tn * 128;
    const int r0 = tid >> 3, c0 = tid & 7;
    float4 aPre[4][2]; int4 bPre[4][2];
    const int lane = tid & 63, w = tid >> 6;
    const int wr = w >> 1, wc = w & 1, fr = lane & 15, fq = lane >> 4;
    f32x4 acc[4][4] = {};

    auto loadTiles = [&](int t) {
        const int k0 = t * 64;
        #pragma unroll
        for (int i = 0; i < 4; i++) {
            const int row = r0 + 32 * i;
            const float4* pa = reinterpret_cast<const float4*>(X + (size_t)(brow + row) * Kdim + k0 + c0 * 8);
            aPre[i][0] = pa[0]; aPre[i][1] = pa[1];
            const int4* pb = reinterpret_cast<const int4*>(W + (size_t)(bcol + row) * Kdim + k0 + c0 * 8);
            bPre[i][0] = pb[0]; bPre[i][1] = pb[1];
        }
    };
    auto writeLDS = [&]() {
        #pragma unroll
        for (int i = 0; i < 4; i++) {
            const int row = r0 + 32 * i;
            const int off = swz_fb(row, c0 * 16);
            short8 va, vb;
            va[0] = (short)f2bf(aPre[i][0].x); va[1] = (short)f2bf(aPre[i][0].y);
            va[2] = (short)f2bf(aPre[i][0].z); va[3] = (short)f2bf(aPre[i][0].w);
            va[4] = (short)f2bf(aPre[i][1].x); va[5] = (short)f2bf(aPre[i][1].y);
            va[6] = (short)f2bf(aPre[i][1].z); va[7] = (short)f2bf(aPre[i][1].w);
            vb[0] = (short)f2bf((float)bPre[i][0].x); vb[1] = (short)f2bf((float)bPre[i][0].y);
            vb[2] = (short)f2bf((float)bPre[i][0].z); vb[3] = (short)f2bf((float)bPre[i][0].w);
            vb[4] = (short)f2bf((float)bPre[i][1].x); vb[5] = (short)f2bf((float)bPre[i][1].y);
            vb[6] = (short)f2bf((float)bPre[i][1].z); vb[7] = (short)f2bf((float)bPre[i][1].w);
            *reinterpret_cast<short8*>(reinterpret_cast<char*>(lA) + off) = va;
            *reinterpret_cast<short8*>(reinterpret_cast<char*>(lB) + off) = vb;
        }
    };

    loadTiles(0);
    for (int t = 0; t < Kdim / 64; t++) {
        writeLDS();
        __syncthreads();
        if (t + 1 < Kdim / 64) loadTiles(t + 1);
        #pragma unroll
        for (int kk = 0; kk < 2; kk++) {
            short8 afv[4], bfv[4];
            const int cb = kk * 64 + fq * 16;
            #pragma unroll
            for (int m = 0; m < 4; m++) {
                const int row = wr * 64 + m * 16 + fr;
                afv[m] = *reinterpret_cast<const short8*>(reinterpret_cast<const char*>(lA) + swz_fb(row, cb));
            }
            #pragma unroll
            for (int n = 0; n < 4; n++) {
                const int row = wc * 64 + n * 16 + fr;
                bfv[n] = *reinterpret_cast<const short8*>(reinterpret_cast<const char*>(lB) + swz_fb(row, cb));
            }
            #pragma unroll
            for (int m = 0; m < 4; m++)
                #pragma unroll
                for (int n = 0; n < 4; n++)
                    acc[m][n] = __builtin_amdgcn_mfma_f32_16x16x32_bf16(afv[m], bfv[n], acc[m][n], 0, 0, 0);
        }
        __syncthreads();
    }
    #pragma unroll
    for (int n = 0; n < 4; n++) {
        const int col = bcol + wc * 64 + n * 16 + fr;
        const float sc = scale[col];
        const float bi = bias[col];
        #pragma unroll
        for (int m = 0; m < 4; m++) {
            const int rbase = brow + wr * 64 + m * 16 + fq * 4;
            #pragma unroll
            for (int j = 0; j < 4; j++)
                Out[(size_t)(rbase + j) * Ndim + col] = acc[m][n][j] * sc + bi;
        }
    }
}

// ---------------------------------------------------------------------------

extern "C" void kernel_launch(void* const* d_in, const int* in_sizes, int n_in,
                              void* d_out, int out_size, void* d_ws, size_t ws_size,
                              hipStream_t stream) {
    const float* x     = (const float*)d_in[0];
    const int*   w8    = (const int*)d_in[1];
    const float* scale = (const float*)d_in[2];
    const float* bias  = (const float*)d_in[3];
    float* out = (float*)d_out;

    const size_t xq_bytes = (size_t)Mdim * Kdim;        // 32 MiB
    const size_t bp_bytes = (size_t)Ndim * Kdim;        // 16 MiB
    const size_t sx_bytes = (size_t)Mdim * sizeof(float);

    if (ws_size >= xq_bytes + bp_bytes + sx_bytes) {
        char*  xq = (char*)d_ws;
        char*  bp = (char*)d_ws + xq_bytes;
        float* sx = (float*)((char*)d_ws + xq_bytes + bp_bytes);
        quant_x_rowwise<<<Mdim, 256, 0, stream>>>(x, xq, sx);
        pack_w_frag<<<(Ndim * Kdim / 16) / 256, 256, 0, stream>>>(w8, bp);
        dim3 grid((Mdim / BM) * (Ndim / BN));           // 32*16 = 512 blocks
        gemm_i8_breg<<<grid, dim3(512), 0, stream>>>(xq, bp, scale, bias, sx, out);
    } else {
        dim3 grid((Mdim / 128) * (Ndim / 128));         // 2048 blocks
        compressed_linear_fb<<<grid, dim3(256), 0, stream>>>(x, w8, scale, bias, out);
    }
}

// Round 12
// 196.269 us; speedup vs baseline: 1.3987x; 1.2237x over previous
//
#include <hip/hip_runtime.h>

// CompressedLinear: out = x[8192,4096] @ (W_int8[4096,4096]*scale)^T + bias.
// Round 12: R7's proven 256x256/8-wave/8-phase int8 skeleton, with phases
// reordered to MFMA-FIRST so ds_reads of cluster q drain on the LDS port
// while cluster q-1 drains on the MFMA pipe (m201's overlap mechanism).
// Cluster schedule (per 2 K-tiles, clusters = (afHalf, ntPair), 8 MFMA each):
//   g1:c00(t) g2:c01(t) g3:c10(t) g4:c11(t) g5:c00(t+1) .. g0':c11(t+1)
// Reads (1 phase ahead of first use):
//   g0': bf(t+2)+afLo(t+2) [16]   g1: afHi(t) [8]   g4: bf(t+1)+afLo(t+1) [16]
//   g5: afHi(t+1) [8]
// Stage rotation (+1 phase vs R7; 2 gloads per call):
//   g1:A11(t+1) g2:B00(t+2) g3:B01(t+2) g4:A00(t+2) g5:A01(t+2)
//   g6:B10(t+3) g7:B11(t+3) g0':A10(t+3)
// Ledger: WAITV4@g3 leaves {B00,B01(t+2)} -> A11(t+1)+older drained -> buf1
//   complete before g4 reads. WAITV4@g7 leaves {B10,B11(t+3)} -> A00,A01(t+2)
//   drained -> buf0 complete before g0' reads. LGKM0 before the barriers at
//   g1/g3/g5/g7 drains each region's reads >=1 phase after issue (free) so
//   the next phase's stage can't race an in-flight ds_read (round-3 lesson).
// Tail: stages stop after A11(31)@tg1; WAITV0@tg3 drains; tg4+ barrier-free.

#define BM 256
#define BN 256
#define BKB 128                 // K-bytes per tile = 128 int8

constexpr int Mdim = 8192;
constexpr int Ndim = 4096;
constexpr int Kdim = 4096;
constexpr int KT = Kdim / BKB;  // 32

typedef __attribute__((ext_vector_type(4)))  int   int32x4;
typedef __attribute__((ext_vector_type(16))) int   int32x16;
typedef __attribute__((ext_vector_type(8)))  short short8;
typedef __attribute__((ext_vector_type(4)))  float f32x4;
typedef unsigned short ushort_t;

__device__ __forceinline__ unsigned short f2bf(float f) {
    union { float f; unsigned u; } v; v.f = f;
    unsigned r = v.u + 0x7FFFu + ((v.u >> 16) & 1u);
    return (unsigned short)(r >> 16);
}

__device__ __forceinline__ void gload_lds16(const void* g, void* l) {
    __builtin_amdgcn_global_load_lds(
        (const __attribute__((address_space(1))) void*)g,
        (__attribute__((address_space(3))) void*)l, 16, 0, 0);
}

#define BARRIER() __builtin_amdgcn_s_barrier()
#define LGKM0()   asm volatile("s_waitcnt lgkmcnt(0)" ::: "memory")
#define WAITV0()  asm volatile("s_waitcnt vmcnt(0)" ::: "memory")
#define WAITV4()  asm volatile("s_waitcnt vmcnt(4)" ::: "memory")
#define WAITV6()  asm volatile("s_waitcnt vmcnt(6)" ::: "memory")

// one cluster: 2 m-tiles x 1 nt x 4 k-steps = 8 MFMA (i8 32x32x32)
#define MFMAC(AF, MB, NH) do {                                               \
    __builtin_amdgcn_s_setprio(1);                                           \
    _Pragma("unroll") for (int mt = 0; mt < 2; ++mt)                         \
    _Pragma("unroll") for (int ks = 0; ks < 4; ++ks)                         \
        acc[(MB)+mt][NH] = __builtin_amdgcn_mfma_i32_32x32x32_i8(            \
            AF[mt][ks], bf[NH][ks], acc[(MB)+mt][NH], 0, 0, 0);              \
    __builtin_amdgcn_s_setprio(0);                                           \
} while (0)

// ---------------- prep kernels ----------------------------------------------

__global__ __launch_bounds__(256)
void quant_x_rowwise(const float* __restrict__ x, char* __restrict__ xq,
                     float* __restrict__ sx) {
    const int row = blockIdx.x;
    const float4* xr = reinterpret_cast<const float4*>(x + (size_t)row * Kdim);
    const int tid = threadIdx.x;
    float4 v[4];
    float am = 0.f;
    #pragma unroll
    for (int j = 0; j < 4; ++j) {
        v[j] = xr[tid + 256 * j];
        am = fmaxf(am, fmaxf(fmaxf(fabsf(v[j].x), fabsf(v[j].y)),
                             fmaxf(fabsf(v[j].z), fabsf(v[j].w))));
    }
    #pragma unroll
    for (int off = 32; off; off >>= 1)
        am = fmaxf(am, __shfl_xor(am, off, 64));
    __shared__ float red[4];
    if ((tid & 63) == 0) red[tid >> 6] = am;
    __syncthreads();
    am = fmaxf(fmaxf(red[0], red[1]), fmaxf(red[2], red[3]));
    am = fmaxf(am, 1e-30f);
    if (tid == 0) sx[row] = am / 127.f;
    const float inv = 127.f / am;
    int* outw = reinterpret_cast<int*>(xq + (size_t)row * Kdim);
    #pragma unroll
    for (int j = 0; j < 4; ++j) {
        const int q0 = (int)rintf(v[j].x * inv) & 255;
        const int q1 = (int)rintf(v[j].y * inv) & 255;
        const int q2 = (int)rintf(v[j].z * inv) & 255;
        const int q3 = (int)rintf(v[j].w * inv) & 255;
        outw[tid + 256 * j] = q0 | (q1 << 8) | (q2 << 16) | (q3 << 24);
    }
}

__global__ __launch_bounds__(256)
void pack_w_int8(const int* __restrict__ w, char* __restrict__ wq, int n4) {
    int idx = blockIdx.x * blockDim.x + threadIdx.x;
    const int stride = gridDim.x * blockDim.x;
    int* out = reinterpret_cast<int*>(wq);
    for (int i = idx; i < n4; i += stride) {
        const int4 a = reinterpret_cast<const int4*>(w)[i];
        out[i] = (a.x & 255) | ((a.y & 255) << 8) |
                 ((a.z & 255) << 16) | ((a.w & 255) << 24);
    }
}

// ---------------- 256x256 pipelined 8-phase int8 GEMM -----------------------

__global__ __launch_bounds__(512, 2)
void gemm_i8_pl(const char* __restrict__ A,   // [M][K] int8
                const char* __restrict__ B,   // [N][K] int8
                const float* __restrict__ scale,
                const float* __restrict__ bias,
                const float* __restrict__ sx,
                float* __restrict__ Out)
{
    // [buf][half: A0,A1,B0,B1][16 KiB] = 128 KiB
    __shared__ __align__(16) char smem[2][4][16384];

    const int tid = threadIdx.x;
    int bid = blockIdx.x;
    bid = (bid & 7) * 64 + (bid >> 3);          // bijective XCD swizzle (512%8==0)
    const int tn = bid & 15;
    const int tm = bid >> 4;
    const int brow = tm * BM;
    const int bcol = tn * BN;

    const int lane = tid & 63;
    const int w    = tid >> 6;                  // 8 waves
    const int wr   = w >> 2;                    // 2 M-waves
    const int wc   = w & 3;                     // 4 N-waves
    const int r32  = lane & 31;
    const int h    = lane >> 5;
    const size_t K1 = (size_t)Kdim;

    // staging (two-level swizzle, proven zero-conflict r6-r11)
    const int swzb = ((lane & 7) ^ (lane >> 3) ^ (w & 3)) << 4;
    const char* aStageSrc = A + (size_t)(brow + w * 8 + (lane >> 3)) * K1 + swzb;
    const char* bStageSrc = B + (size_t)(bcol + w * 8 + (lane >> 3)) * K1 + swzb;

    auto stageA = [&](int bufb, int hh, int tt) {   // 2 gloads
        const char* s = aStageSrc + (size_t)(hh * 128) * K1 + (size_t)tt * BKB;
        char* d = &smem[bufb][hh][w * 1024];
        gload_lds16(s, d);
        gload_lds16(s + 64 * K1, d + 8192);
    };
    auto stageB = [&](int bufb, int hh, int tt) {
        const char* s = bStageSrc + (size_t)(hh * 128) * K1 + (size_t)tt * BKB;
        char* d = &smem[bufb][2 + hh][w * 1024];
        gload_lds16(s, d);
        gload_lds16(s + 64 * K1, d + 8192);
    };

    const char* aBase[2] = { &smem[0][wr][0] + r32 * 128,
                             &smem[1][wr][0] + r32 * 128 };
    const char* bBase[2] = { &smem[0][2 + (wc >> 1)][0] + ((wc & 1) * 64 + r32) * 128,
                             &smem[1][2 + (wc >> 1)][0] + ((wc & 1) * 64 + r32) * 128 };
    const int frx = ((r32 & 7) ^ (r32 >> 3)) << 4;
    int colb[4];
    #pragma unroll
    for (int ks = 0; ks < 4; ++ks) colb[ks] = (ks * 32 + h * 16) ^ frx;

    int32x16 acc[4][2] = {};             // [m-tile][n-tile]
    int32x4 afLo[2][4], afHi[2][4], bf[2][4];

    auto ldB = [&](const char* base) {
        #pragma unroll
        for (int nt = 0; nt < 2; ++nt)
            #pragma unroll
            for (int ks = 0; ks < 4; ++ks)
                bf[nt][ks] = *reinterpret_cast<const int32x4*>(base + nt * 4096 + colb[ks]);
    };
    auto ldALo = [&](const char* base) {
        #pragma unroll
        for (int mt = 0; mt < 2; ++mt)
            #pragma unroll
            for (int ks = 0; ks < 4; ++ks)
                afLo[mt][ks] = *reinterpret_cast<const int32x4*>(base + mt * 4096 + colb[ks]);
    };
    auto ldAHi = [&](const char* base) {
        #pragma unroll
        for (int mt = 0; mt < 2; ++mt)
            #pragma unroll
            for (int ks = 0; ks < 4; ++ks)
                afHi[mt][ks] = *reinterpret_cast<const int32x4*>(base + (2 + mt) * 4096 + colb[ks]);
    };

    // ---- prologue: buf0 <- t0 full (8 ops), buf1 <- t1 {B0,B1,A0} (6 ops)
    stageB(0, 0, 0); stageB(0, 1, 0); stageA(0, 0, 0); stageA(0, 1, 0);
    stageB(1, 0, 1); stageB(1, 1, 1); stageA(1, 0, 1);
    WAITV6();          // buf0's 8 drained; {B10,B11,A10}(t1) may fly
    BARRIER();
    // peeled g0': first-tile reads (no MFMA yet, no stage — A11(1) goes @ g1)
    ldB(bBase[0]);
    ldALo(aBase[0]);
    BARRIER();

    // ---- main loop: 15 pairs (t = 0..29) ----
    for (int i = 0; i < KT / 2 - 1; ++i) {
        const int t = 2 * i;

        // g1: c00(t) | read afHi(t) | stage A11(t+1)
        MFMAC(afLo, 0, 0);
        ldAHi(aBase[0]);
        stageA(1, 1, t + 1);
        LGKM0();                 // drains g0' reads (B,A of buf0) + afHi: >=ok
        BARRIER();
        // g2: c01(t) | stage B00(t+2)
        MFMAC(afLo, 0, 1);
        stageB(0, 0, t + 2);
        BARRIER();
        // g3: c10(t) | stage B01(t+2) | buf1 complete
        MFMAC(afHi, 2, 0);
        stageB(0, 1, t + 2);
        LGKM0();                 // buf0.A reads drained before g4's A-stage
        WAITV4();                // leaves {B00,B01(t+2)}: A11(t+1)+older landed
        BARRIER();
        // g4: c11(t) | read bf,afLo (t+1) | stage A00(t+2)
        MFMAC(afHi, 2, 1);
        ldB(bBase[1]);
        ldALo(aBase[1]);
        stageA(0, 0, t + 2);
        BARRIER();
        // g5: c00(t+1) | read afHi(t+1) | stage A01(t+2)
        MFMAC(afLo, 0, 0);
        ldAHi(aBase[1]);
        stageA(0, 1, t + 2);
        LGKM0();                 // buf1.B reads drained before g6's B-stage
        BARRIER();
        // g6: c01(t+1) | stage B10(t+3)
        MFMAC(afLo, 0, 1);
        stageB(1, 0, t + 3);
        BARRIER();
        // g7: c10(t+1) | stage B11(t+3) | buf0 complete
        MFMAC(afHi, 2, 0);
        stageB(1, 1, t + 3);
        LGKM0();                 // buf1.A reads drained before g0's A-stage
        WAITV4();                // leaves {B10,B11(t+3)}: A00,A01(t+2) landed
        BARRIER();
        // g0': c11(t+1) | read bf,afLo (t+2) | stage A10(t+3)
        MFMAC(afHi, 2, 1);
        ldB(bBase[0]);
        ldALo(aBase[0]);
        stageA(1, 0, t + 3);
        BARRIER();
    }

    // ---- tail pair (30, 31): entering with bf,afLo = tile 30; buf1<-31
    //      missing only A11(31).
    {
        // tg1: c00(30) | read afHi(30) | stage A11(31)
        MFMAC(afLo, 0, 0);
        ldAHi(aBase[0]);
        stageA(1, 1, KT - 1);
        LGKM0();
        BARRIER();
        // tg2: c01(30)
        MFMAC(afLo, 0, 1);
        BARRIER();
        // tg3: c10(30) | drain all stages -> buf1(31) complete
        MFMAC(afHi, 2, 0);
        WAITV0();
        BARRIER();
        // tg4+: no LDS writes remain; data deps order reads vs MFMA
        MFMAC(afHi, 2, 1);
        ldB(bBase[1]);
        ldALo(aBase[1]);
        MFMAC(afLo, 0, 0);
        ldAHi(aBase[1]);
        MFMAC(afLo, 0, 1);
        MFMAC(afHi, 2, 0);
        MFMAC(afHi, 2, 1);
    }

    // epilogue: out = acc * scale[col] * scale_x[row] + bias[col]
    // C/D (32x32): col=lane&31, row=(reg&3)+8*(reg>>2)+4*(lane>>5)
    #pragma unroll
    for (int nt = 0; nt < 2; ++nt) {
        const int col = bcol + wc * 64 + nt * 32 + r32;
        const float sc = scale[col];
        const float bi = bias[col];
        #pragma unroll
        for (int mt = 0; mt < 4; ++mt) {
            const int rb = brow + wr * 128 + mt * 32 + 4 * h;
            #pragma unroll
            for (int q = 0; q < 4; ++q) {
                const int r4 = rb + 8 * q;
                #pragma unroll
                for (int r = 0; r < 4; ++r) {
                    const float sxr = sx[r4 + r];
                    Out[(size_t)(r4 + r) * Ndim + col] =
                        (float)acc[mt][nt][q * 4 + r] * (sc * sxr) + bi;
                }
            }
        }
    }
}

// ---------------- fallback (round-1 kernel) if ws too small -----------------

__device__ __forceinline__ int swz_fb(int row, int colbyte) {
    return row * 128 + (colbyte ^ ((row & 7) << 4));
}

__global__ __launch_bounds__(256)
void compressed_linear_fb(const float* __restrict__ X,
                          const int*   __restrict__ W,
                          const float* __restrict__ scale,
                          const float* __restrict__ bias,
                          float* __restrict__ Out)
{
    __shared__ __align__(16) ushort_t lA[128 * 64];
    __shared__ __align__(16) ushort_t lB[128 * 64];
    const int tid = threadIdx.x;
    const int bid = blockIdx.x;
    const int tn = bid & 31, tm = bid >> 5;
    const int brow = tm * 128, bcol = tn * 128;
    const int r0 = tid >> 3, c0 = tid & 7;
    float4 aPre[4][2]; int4 bPre[4][2];
    const int lane = tid & 63, w = tid >> 6;
    const int wr = w >> 1, wc = w & 1, fr = lane & 15, fq = lane >> 4;
    f32x4 acc[4][4] = {};

    auto loadTiles = [&](int t) {
        const int k0 = t * 64;
        #pragma unroll
        for (int i = 0; i < 4; i++) {
            const int row = r0 + 32 * i;
            const float4* pa = reinterpret_cast<const float4*>(X + (size_t)(brow + row) * Kdim + k0 + c0 * 8);
            aPre[i][0] = pa[0]; aPre[i][1] = pa[1];
            const int4* pb = reinterpret_cast<const int4*>(W + (size_t)(bcol + row) * Kdim + k0 + c0 * 8);
            bPre[i][0] = pb[0]; bPre[i][1] = pb[1];
        }
    };
    auto writeLDS = [&]() {
        #pragma unroll
        for (int i = 0; i < 4; i++) {
            const int row = r0 + 32 * i;
            const int off = swz_fb(row, c0 * 16);
            short8 va, vb;
            va[0] = (short)f2bf(aPre[i][0].x); va[1] = (short)f2bf(aPre[i][0].y);
            va[2] = (short)f2bf(aPre[i][0].z); va[3] = (short)f2bf(aPre[i][0].w);
            va[4] = (short)f2bf(aPre[i][1].x); va[5] = (short)f2bf(aPre[i][1].y);
            va[6] = (short)f2bf(aPre[i][1].z); va[7] = (short)f2bf(aPre[i][1].w);
            vb[0] = (short)f2bf((float)bPre[i][0].x); vb[1] = (short)f2bf((float)bPre[i][0].y);
            vb[2] = (short)f2bf((float)bPre[i][0].z); vb[3] = (short)f2bf((float)bPre[i][0].w);
            vb[4] = (short)f2bf((float)bPre[i][1].x); vb[5] = (short)f2bf((float)bPre[i][1].y);
            vb[6] = (short)f2bf((float)bPre[i][1].z); vb[7] = (short)f2bf((float)bPre[i][1].w);
            *reinterpret_cast<short8*>(reinterpret_cast<char*>(lA) + off) = va;
            *reinterpret_cast<short8*>(reinterpret_cast<char*>(lB) + off) = vb;
        }
    };

    loadTiles(0);
    for (int t = 0; t < Kdim / 64; t++) {
        writeLDS();
        __syncthreads();
        if (t + 1 < Kdim / 64) loadTiles(t + 1);
        #pragma unroll
        for (int kk = 0; kk < 2; kk++) {
            short8 afv[4], bfv[4];
            const int cb = kk * 64 + fq * 16;
            #pragma unroll
            for (int m = 0; m < 4; m++) {
                const int row = wr * 64 + m * 16 + fr;
                afv[m] = *reinterpret_cast<const short8*>(reinterpret_cast<const char*>(lA) + swz_fb(row, cb));
            }
            #pragma unroll
            for (int n = 0; n < 4; n++) {
                const int row = wc * 64 + n * 16 + fr;
                bfv[n] = *reinterpret_cast<const short8*>(reinterpret_cast<const char*>(lB) + swz_fb(row, cb));
            }
            #pragma unroll
            for (int m = 0; m < 4; m++)
                #pragma unroll
                for (int n = 0; n < 4; n++)
                    acc[m][n] = __builtin_amdgcn_mfma_f32_16x16x32_bf16(afv[m], bfv[n], acc[m][n], 0, 0, 0);
        }
        __syncthreads();
    }
    #pragma unroll
    for (int n = 0; n < 4; n++) {
        const int col = bcol + wc * 64 + n * 16 + fr;
        const float sc = scale[col];
        const float bi = bias[col];
        #pragma unroll
        for (int m = 0; m < 4; m++) {
            const int rbase = brow + wr * 64 + m * 16 + fq * 4;
            #pragma unroll
            for (int j = 0; j < 4; j++)
                Out[(size_t)(rbase + j) * Ndim + col] = acc[m][n][j] * sc + bi;
        }
    }
}

// ---------------------------------------------------------------------------

extern "C" void kernel_launch(void* const* d_in, const int* in_sizes, int n_in,
                              void* d_out, int out_size, void* d_ws, size_t ws_size,
                              hipStream_t stream) {
    const float* x     = (const float*)d_in[0];
    const int*   w8    = (const int*)d_in[1];
    const float* scale = (const float*)d_in[2];
    const float* bias  = (const float*)d_in[3];
    float* out = (float*)d_out;

    const size_t xq_bytes = (size_t)Mdim * Kdim;        // 32 MiB
    const size_t wq_bytes = (size_t)Ndim * Kdim;        // 16 MiB
    const size_t sx_bytes = (size_t)Mdim * sizeof(float);

    if (ws_size >= xq_bytes + wq_bytes + sx_bytes) {
        char*  xq = (char*)d_ws;
        char*  wq = (char*)d_ws + xq_bytes;
        float* sx = (float*)((char*)d_ws + xq_bytes + wq_bytes);
        quant_x_rowwise<<<Mdim, 256, 0, stream>>>(x, xq, sx);
        pack_w_int8<<<2048, 256, 0, stream>>>(w8, wq, (Ndim * Kdim) / 4);
        dim3 grid((Mdim / BM) * (Ndim / BN));           // 512 blocks
        gemm_i8_pl<<<grid, dim3(512), 0, stream>>>(xq, wq, scale, bias, sx, out);
    } else {
        dim3 grid((Mdim / 128) * (Ndim / 128));
        compressed_linear_fb<<<grid, dim3(256), 0, stream>>>(x, w8, scale, bias, out);
    }
}

// Round 13
// 189.174 us; speedup vs baseline: 1.4512x; 1.0375x over previous
//
#include <hip/hip_runtime.h>

// CompressedLinear: out = x[8192,4096] @ (W_int8[4096,4096]*scale)^T + bias.
// Round 13: consolidation. R7's champion (GEMM 147us, 42% of i8 peak; best of
// 6 schedule variants R7-R12) with one zero-risk tweak: MFMA cluster issues
// ks-OUTER so consecutive MFMAs are independent (R7 had kk-innermost =
// back-to-back dependent accumulator chains). Epilogue sx loads hoisted.
//
// Evidence for this structure being the plain-HIP plateau here:
//   R7 8-phase=147, R9 merged=153, R12 MFMA-first+read-lead=150 (all ~42%);
//   R8 small-tile=188 (locality), R10 1-barrier=255, R11 B-in-reg=218.
//   Occupancy register-capped at 8 waves/CU (acc 128 AGPR + 128 VGPR).
// Stage rotation + WAITV6 ledger + peeled tail: proven rounds 4-7.

#define BM 256
#define BN 256
#define BKB 128                 // K-bytes per tile = 128 int8

constexpr int Mdim = 8192;
constexpr int Ndim = 4096;
constexpr int Kdim = 4096;
constexpr int KT = Kdim / BKB;  // 32

typedef __attribute__((ext_vector_type(4)))  int   int32x4;
typedef __attribute__((ext_vector_type(16))) int   int32x16;
typedef __attribute__((ext_vector_type(8)))  short short8;
typedef __attribute__((ext_vector_type(4)))  float f32x4;
typedef unsigned short ushort_t;

__device__ __forceinline__ unsigned short f2bf(float f) {
    union { float f; unsigned u; } v; v.f = f;
    unsigned r = v.u + 0x7FFFu + ((v.u >> 16) & 1u);
    return (unsigned short)(r >> 16);
}

__device__ __forceinline__ void gload_lds16(const void* g, void* l) {
    __builtin_amdgcn_global_load_lds(
        (const __attribute__((address_space(1))) void*)g,
        (__attribute__((address_space(3))) void*)l, 16, 0, 0);
}

#define BARRIER() __builtin_amdgcn_s_barrier()
#define LGKM0()   asm volatile("s_waitcnt lgkmcnt(0)" ::: "memory")
#define WAITV0()  asm volatile("s_waitcnt vmcnt(0)" ::: "memory")
#define WAITV6()  asm volatile("s_waitcnt vmcnt(6)" ::: "memory")

// one quadrant: 2 m-tiles x 1 n-tile x 4 k-steps = 8 MFMA (i8 32x32x32).
// ks OUTER: consecutive MFMAs (mt varies) are independent; the dependent
// accumulate chain re-visits acc[.] only every 2 instructions.
#define MFMAQ(MH, NH) do {                                                   \
    __builtin_amdgcn_s_setprio(1);                                           \
    _Pragma("unroll") for (int ks = 0; ks < 4; ++ks)                         \
    _Pragma("unroll") for (int mt = 0; mt < 2; ++mt)                         \
        acc[(MH)*2+mt][NH] = __builtin_amdgcn_mfma_i32_32x32x32_i8(          \
            af[mt][ks], bf[NH][ks], acc[(MH)*2+mt][NH], 0, 0, 0);            \
    __builtin_amdgcn_s_setprio(0);                                           \
} while (0)

// ---------------- prep kernels ----------------------------------------------

// per-row symmetric int8 quantization of x; one block per row
__global__ __launch_bounds__(256)
void quant_x_rowwise(const float* __restrict__ x, char* __restrict__ xq,
                     float* __restrict__ sx) {
    const int row = blockIdx.x;
    const float4* xr = reinterpret_cast<const float4*>(x + (size_t)row * Kdim);
    const int tid = threadIdx.x;
    float4 v[4];
    float am = 0.f;
    #pragma unroll
    for (int j = 0; j < 4; ++j) {
        v[j] = xr[tid + 256 * j];
        am = fmaxf(am, fmaxf(fmaxf(fabsf(v[j].x), fabsf(v[j].y)),
                             fmaxf(fabsf(v[j].z), fabsf(v[j].w))));
    }
    #pragma unroll
    for (int off = 32; off; off >>= 1)
        am = fmaxf(am, __shfl_xor(am, off, 64));
    __shared__ float red[4];
    if ((tid & 63) == 0) red[tid >> 6] = am;
    __syncthreads();
    am = fmaxf(fmaxf(red[0], red[1]), fmaxf(red[2], red[3]));
    am = fmaxf(am, 1e-30f);
    if (tid == 0) sx[row] = am / 127.f;
    const float inv = 127.f / am;
    int* outw = reinterpret_cast<int*>(xq + (size_t)row * Kdim);
    #pragma unroll
    for (int j = 0; j < 4; ++j) {
        const int q0 = (int)rintf(v[j].x * inv) & 255;
        const int q1 = (int)rintf(v[j].y * inv) & 255;
        const int q2 = (int)rintf(v[j].z * inv) & 255;
        const int q3 = (int)rintf(v[j].w * inv) & 255;
        outw[tid + 256 * j] = q0 | (q1 << 8) | (q2 << 16) | (q3 << 24);
    }
}

// pack W int32 (values in [-128,127]) -> int8
__global__ __launch_bounds__(256)
void pack_w_int8(const int* __restrict__ w, char* __restrict__ wq, int n4) {
    int idx = blockIdx.x * blockDim.x + threadIdx.x;
    const int stride = gridDim.x * blockDim.x;
    int* out = reinterpret_cast<int*>(wq);
    for (int i = idx; i < n4; i += stride) {
        const int4 a = reinterpret_cast<const int4*>(w)[i];
        out[i] = (a.x & 255) | ((a.y & 255) << 8) |
                 ((a.z & 255) << 16) | ((a.w & 255) << 24);
    }
}

// ---------------- 256x256 8-phase int8 GEMM ---------------------------------

__global__ __launch_bounds__(512, 2)
void gemm_i8_8phase(const char* __restrict__ A,   // [M][K] int8
                    const char* __restrict__ B,   // [N][K] int8
                    const float* __restrict__ scale,
                    const float* __restrict__ bias,
                    const float* __restrict__ sx,
                    float* __restrict__ Out)
{
    // [buf][half: A0,A1,B0,B1][16 KiB] = 128 KiB
    __shared__ __align__(16) char smem[2][4][16384];

    const int tid = threadIdx.x;
    int bid = blockIdx.x;
    bid = (bid & 7) * 64 + (bid >> 3);          // bijective XCD swizzle (512%8==0)
    const int tn = bid & 15;                    // N/BN = 16
    const int tm = bid >> 4;                    // M/BM = 32
    const int brow = tm * BM;
    const int bcol = tn * BN;

    const int lane = tid & 63;
    const int w    = tid >> 6;                  // 8 waves
    const int wr   = w >> 2;                    // 2 M-waves
    const int wc   = w & 3;                     // 4 N-waves
    const int r32  = lane & 31;
    const int h    = lane >> 5;                 // k-group
    const size_t K1 = (size_t)Kdim;             // row stride in bytes (int8)

    // staging source (pre-swizzled global address; LDS dest stays linear)
    // two-level swizzle nibble = (l&7) ^ (row&7) ^ ((row>>3)&3)
    const int swzb = ((lane & 7) ^ (lane >> 3) ^ (w & 3)) << 4;
    const char* aStageSrc = A + (size_t)(brow + w * 8 + (lane >> 3)) * K1 + swzb;
    const char* bStageSrc = B + (size_t)(bcol + w * 8 + (lane >> 3)) * K1 + swzb;

    auto stageA = [&](int bufb, int hh, int tt) {
        const char* s = aStageSrc + (size_t)(hh * 128) * K1 + (size_t)tt * BKB;
        char* d = &smem[bufb][hh][w * 1024];
        gload_lds16(s, d);
        gload_lds16(s + 64 * K1, d + 8192);
    };
    auto stageB = [&](int bufb, int hh, int tt) {
        const char* s = bStageSrc + (size_t)(hh * 128) * K1 + (size_t)tt * BKB;
        char* d = &smem[bufb][2 + hh][w * 1024];
        gload_lds16(s, d);
        gload_lds16(s + 64 * K1, d + 8192);
    };

    // ds_read bases (row stride 128B; proven zero-conflict geometry)
    const char* aBase[2] = { &smem[0][wr][0] + r32 * 128,
                             &smem[1][wr][0] + r32 * 128 };
    const char* bBase[2] = { &smem[0][2 + (wc >> 1)][0] + ((wc & 1) * 64 + r32) * 128,
                             &smem[1][2 + (wc >> 1)][0] + ((wc & 1) * 64 + r32) * 128 };
    const int frx = ((r32 & 7) ^ (r32 >> 3)) << 4;
    int colb[4];
    #pragma unroll
    for (int ks = 0; ks < 4; ++ks) colb[ks] = (ks * 32 + h * 16) ^ frx;

    int32x16 acc[4][2] = {};     // [m-tile][n-tile]
    int32x4 af[2][4], bf[2][4];  // [tile][k-step], 16 int8 each

    auto ldA = [&](const char* base, int MH) {
        #pragma unroll
        for (int mt = 0; mt < 2; ++mt) {
            const char* p = base + ((MH) * 2 + mt) * 4096;   // 32 rows * 128B
            #pragma unroll
            for (int ks = 0; ks < 4; ++ks)
                af[mt][ks] = *reinterpret_cast<const int32x4*>(p + colb[ks]);
        }
    };
    auto ldB = [&](const char* base) {
        #pragma unroll
        for (int nt = 0; nt < 2; ++nt) {
            const char* p = base + nt * 4096;
            #pragma unroll
            for (int ks = 0; ks < 4; ++ks)
                bf[nt][ks] = *reinterpret_cast<const int32x4*>(p + colb[ks]);
        }
    };

    // ---- prologue: t0 full + t1 {B0,B1,A0}; t1's 3 halves may stay in flight
    stageB(0, 0, 0); stageB(0, 1, 0); stageA(0, 0, 0); stageA(0, 1, 0);
    stageB(1, 0, 1); stageB(1, 1, 1); stageA(1, 0, 1);
    WAITV6();          // oldest 8 ops (= all of t0/buf0) landed
    BARRIER();

    // ---- main loop: 15 iterations, all stages unconditional ----
    for (int i = 0; i < KT / 2 - 1; ++i) {
        const int t = 2 * i;

        // g0: q0 of t (buf0)
        ldB(bBase[0]); ldA(aBase[0], 0);
        stageA(1, 1, t + 1);
        BARRIER(); LGKM0();
        MFMAQ(0, 0);
        BARRIER();
        // g1
        stageB(0, 0, t + 2);
        BARRIER(); LGKM0();
        MFMAQ(0, 1);
        BARRIER();
        // g2
        ldA(aBase[0], 1);
        stageB(0, 1, t + 2);
        BARRIER(); LGKM0();
        MFMAQ(1, 0);
        BARRIER();
        // g3 (+ K-tile wait: buf1/t+1 landed; 3 newer half-tiles in flight)
        stageA(0, 0, t + 2);
        BARRIER(); LGKM0();
        MFMAQ(1, 1);
        WAITV6();
        BARRIER();
        // g4: q0 of t+1 (buf1)
        ldB(bBase[1]); ldA(aBase[1], 0);
        stageA(0, 1, t + 2);
        BARRIER(); LGKM0();
        MFMAQ(0, 0);
        BARRIER();
        // g5
        stageB(1, 0, t + 3);
        BARRIER(); LGKM0();
        MFMAQ(0, 1);
        BARRIER();
        // g6
        ldA(aBase[1], 1);
        stageB(1, 1, t + 3);
        BARRIER(); LGKM0();
        MFMAQ(1, 0);
        BARRIER();
        // g7 (+ K-tile wait: buf0/t+2 landed; 3 newer half-tiles in flight)
        stageA(1, 0, t + 3);
        BARRIER(); LGKM0();
        MFMAQ(1, 1);
        WAITV6();
        BARRIER();
    }

    // ---- peeled tail: t = KT-2; only remaining stage is (buf1.A1, KT-1).
    //      Full drain at g3 so buf1/t+1 is guaranteed landed before g4/g6.
    {
        // g0
        ldB(bBase[0]); ldA(aBase[0], 0);
        stageA(1, 1, KT - 1);
        BARRIER(); LGKM0();
        MFMAQ(0, 0);
        BARRIER();
        // g1
        MFMAQ(0, 1);
        BARRIER();
        // g2
        ldA(aBase[0], 1);
        BARRIER(); LGKM0();
        MFMAQ(1, 0);
        BARRIER();
        // g3: drain everything
        MFMAQ(1, 1);
        WAITV0();
        BARRIER();
        // g4
        ldB(bBase[1]); ldA(aBase[1], 0);
        BARRIER(); LGKM0();
        MFMAQ(0, 0);
        // g5
        MFMAQ(0, 1);
        // g6
        ldA(aBase[1], 1);
        LGKM0();
        MFMAQ(1, 0);
        // g7
        MFMAQ(1, 1);
    }

    // epilogue: out = acc * scale[col] * scale_x[row] + bias[col]
    // C/D (32x32): col=lane&31, row=(reg&3)+8*(reg>>2)+4*(lane>>5)
    #pragma unroll
    for (int mt = 0; mt < 4; ++mt) {
        const int rb = brow + wr * 128 + mt * 32 + 4 * h;
        float sxr[4][4];
        #pragma unroll
        for (int q = 0; q < 4; ++q)
            #pragma unroll
            for (int r = 0; r < 4; ++r)
                sxr[q][r] = sx[rb + 8 * q + r];
        #pragma unroll
        for (int nt = 0; nt < 2; ++nt) {
            const int col = bcol + wc * 64 + nt * 32 + r32;
            const float sc = scale[col];
            const float bi = bias[col];
            #pragma unroll
            for (int q = 0; q < 4; ++q) {
                const int r4 = rb + 8 * q;
                #pragma unroll
                for (int r = 0; r < 4; ++r) {
                    Out[(size_t)(r4 + r) * Ndim + col] =
                        (float)acc[mt][nt][q * 4 + r] * (sc * sxr[q][r]) + bi;
                }
            }
        }
    }
}

// ---------------- fallback (round-1 kernel) if ws too small -----------------

__device__ __forceinline__ int swz_fb(int row, int colbyte) {
    return row * 128 + (colbyte ^ ((row & 7) << 4));
}

__global__ __launch_bounds__(256)
void compressed_linear_fb(const float* __restrict__ X,
                          const int*   __restrict__ W,
                          const float* __restrict__ scale,
                          const float* __restrict__ bias,
                          float* __restrict__ Out)
{
    __shared__ __align__(16) ushort_t lA[128 * 64];
    __shared__ __align__(16) ushort_t lB[128 * 64];
    const int tid = threadIdx.x;
    const int bid = blockIdx.x;
    const int tn = bid & 31, tm = bid >> 5;
    const int brow = tm * 128, bcol = tn * 128;
    const int r0 = tid >> 3, c0 = tid & 7;
    float4 aPre[4][2]; int4 bPre[4][2];
    const int lane = tid & 63, w = tid >> 6;
    const int wr = w >> 1, wc = w & 1, fr = lane & 15, fq = lane >> 4;
    f32x4 acc[4][4] = {};

    auto loadTiles = [&](int t) {
        const int k0 = t * 64;
        #pragma unroll
        for (int i = 0; i < 4; i++) {
            const int row = r0 + 32 * i;
            const float4* pa = reinterpret_cast<const float4*>(X + (size_t)(brow + row) * Kdim + k0 + c0 * 8);
            aPre[i][0] = pa[0]; aPre[i][1] = pa[1];
            const int4* pb = reinterpret_cast<const int4*>(W + (size_t)(bcol + row) * Kdim + k0 + c0 * 8);
            bPre[i][0] = pb[0]; bPre[i][1] = pb[1];
        }
    };
    auto writeLDS = [&]() {
        #pragma unroll
        for (int i = 0; i < 4; i++) {
            const int row = r0 + 32 * i;
            const int off = swz_fb(row, c0 * 16);
            short8 va, vb;
            va[0] = (short)f2bf(aPre[i][0].x); va[1] = (short)f2bf(aPre[i][0].y);
            va[2] = (short)f2bf(aPre[i][0].z); va[3] = (short)f2bf(aPre[i][0].w);
            va[4] = (short)f2bf(aPre[i][1].x); va[5] = (short)f2bf(aPre[i][1].y);
            va[6] = (short)f2bf(aPre[i][1].z); va[7] = (short)f2bf(aPre[i][1].w);
            vb[0] = (short)f2bf((float)bPre[i][0].x); vb[1] = (short)f2bf((float)bPre[i][0].y);
            vb[2] = (short)f2bf((float)bPre[i][0].z); vb[3] = (short)f2bf((float)bPre[i][0].w);
            vb[4] = (short)f2bf((float)bPre[i][1].x); vb[5] = (short)f2bf((float)bPre[i][1].y);
            vb[6] = (short)f2bf((float)bPre[i][1].z); vb[7] = (short)f2bf((float)bPre[i][1].w);
            *reinterpret_cast<short8*>(reinterpret_cast<char*>(lA) + off) = va;
            *reinterpret_cast<short8*>(reinterpret_cast<char*>(lB) + off) = vb;
        }
    };

    loadTiles(0);
    for (int t = 0; t < Kdim / 64; t++) {
        writeLDS();
        __syncthreads();
        if (t + 1 < Kdim / 64) loadTiles(t + 1);
        #pragma unroll
        for (int kk = 0; kk < 2; kk++) {
            short8 afv[4], bfv[4];
            const int cb = kk * 64 + fq * 16;
            #pragma unroll
            for (int m = 0; m < 4; m++) {
                const int row = wr * 64 + m * 16 + fr;
                afv[m] = *reinterpret_cast<const short8*>(reinterpret_cast<const char*>(lA) + swz_fb(row, cb));
            }
            #pragma unroll
            for (int n = 0; n < 4; n++) {
                const int row = wc * 64 + n * 16 + fr;
                bfv[n] = *reinterpret_cast<const short8*>(reinterpret_cast<const char*>(lB) + swz_fb(row, cb));
            }
            #pragma unroll
            for (int m = 0; m < 4; m++)
                #pragma unroll
                for (int n = 0; n < 4; n++)
                    acc[m][n] = __builtin_amdgcn_mfma_f32_16x16x32_bf16(afv[m], bfv[n], acc[m][n], 0, 0, 0);
        }
        __syncthreads();
    }
    #pragma unroll
    for (int n = 0; n < 4; n++) {
        const int col = bcol + wc * 64 + n * 16 + fr;
        const float sc = scale[col];
        const float bi = bias[col];
        #pragma unroll
        for (int m = 0; m < 4; m++) {
            const int rbase = brow + wr * 64 + m * 16 + fq * 4;
            #pragma unroll
            for (int j = 0; j < 4; j++)
                Out[(size_t)(rbase + j) * Ndim + col] = acc[m][n][j] * sc + bi;
        }
    }
}

// ---------------------------------------------------------------------------

extern "C" void kernel_launch(void* const* d_in, const int* in_sizes, int n_in,
                              void* d_out, int out_size, void* d_ws, size_t ws_size,
                              hipStream_t stream) {
    const float* x     = (const float*)d_in[0];
    const int*   w8    = (const int*)d_in[1];
    const float* scale = (const float*)d_in[2];
    const float* bias  = (const float*)d_in[3];
    float* out = (float*)d_out;

    const size_t xq_bytes = (size_t)Mdim * Kdim;        // 32 MiB
    const size_t wq_bytes = (size_t)Ndim * Kdim;        // 16 MiB
    const size_t sx_bytes = (size_t)Mdim * sizeof(float);

    if (ws_size >= xq_bytes + wq_bytes + sx_bytes) {
        char*  xq = (char*)d_ws;
        char*  wq = (char*)d_ws + xq_bytes;
        float* sx = (float*)((char*)d_ws + xq_bytes + wq_bytes);
        quant_x_rowwise<<<Mdim, 256, 0, stream>>>(x, xq, sx);
        pack_w_int8<<<2048, 256, 0, stream>>>(w8, wq, (Ndim * Kdim) / 4);
        dim3 grid((Mdim / BM) * (Ndim / BN));           // 32*16 = 512 blocks
        gemm_i8_8phase<<<grid, dim3(512), 0, stream>>>(xq, wq, scale, bias, sx, out);
    } else {
        dim3 grid((Mdim / 128) * (Ndim / 128));         // 2048 blocks
        compressed_linear_fb<<<grid, dim3(256), 0, stream>>>(x, w8, scale, bias, out);
    }
}

// Round 14
// 189.048 us; speedup vs baseline: 1.4521x; 1.0007x over previous
//
#include <hip/hip_runtime.h>

// CompressedLinear: out = x[8192,4096] @ (W_int8[4096,4096]*scale)^T + bias.
// Round 14: even read spread. R13's phases issued 16/0/8/0 ds_reads -> the
// 16-read phases stall MFMA on LDS-port drain, 0-read phases idle the port
// (MfmaUtil stuck 44%; m201 with 4-8 reads/phase hits 62%). New cut: each
// phase = 1 m-tile cluster (8 MFMA) + 4 reads (af group, one phase ahead);
// bf read once per tile at P3 AFTER its last use (WAR by program order).
// 1 barrier/phase (8 per 2 K-tiles, was 16). Registers unchanged (~124).
//
// Per tile tau (p = tau&1; buf p holds tau):
//  P0: BAR; stageA0(tau+1)->buf(1-p); CL(afA,mt0); read af1->afB
//  P1: BAR; stageA1(tau+1); stageB0(tau+2)->buf(p); CL(afB,mt1); read af2->afA
//  P2: BAR; stageB1(tau+2); CL(afA,mt2); read af3->afB; WAITV4
//  P3: BAR; CL(afB,mt3); read af0(tau+1)->afA; read bf(tau+1)
// Structural safety (no timing assumptions):
//  - stage X only after every wave's cluster CONSUMING X's last reads has
//    retired + a barrier: A(tau+1)@P0/P1 is 1 full phase after af3(tau-1)'s
//    consuming cluster; B(tau+2)@P1/P2 is >=1 phase after bf(tau)'s P0 use.
//  - WAITV4@P2-end queue: [A0(tau+1)@P0][A1(tau+1)@P1][B0(tau+2)@P1]
//    [B1(tau+2)@P2] = 8 ops -> leaves B(tau+2), drains A(tau+1) and all
//    older => buf(tau+1) complete before P3's reads (barrier P3 publishes).
//  - Prologue: t0 full + B0,B1(t1) = 12 ops, WAITV4 drains t0. Tile 0
//    stages A(1)@P0/P1 -> steady state. Tail: tile 30 skips B-stages,
//    WAITV0@P2 (drains A(31)); tile 31 stages/reads nothing extra.

#define BM 256
#define BN 256
#define BKB 128                 // K-bytes per tile = 128 int8

constexpr int Mdim = 8192;
constexpr int Ndim = 4096;
constexpr int Kdim = 4096;
constexpr int KT = Kdim / BKB;  // 32

typedef __attribute__((ext_vector_type(4)))  int   int32x4;
typedef __attribute__((ext_vector_type(16))) int   int32x16;
typedef __attribute__((ext_vector_type(8)))  short short8;
typedef __attribute__((ext_vector_type(4)))  float f32x4;
typedef unsigned short ushort_t;

__device__ __forceinline__ unsigned short f2bf(float f) {
    union { float f; unsigned u; } v; v.f = f;
    unsigned r = v.u + 0x7FFFu + ((v.u >> 16) & 1u);
    return (unsigned short)(r >> 16);
}

__device__ __forceinline__ void gload_lds16(const void* g, void* l) {
    __builtin_amdgcn_global_load_lds(
        (const __attribute__((address_space(1))) void*)g,
        (__attribute__((address_space(3))) void*)l, 16, 0, 0);
}

#define BARRIER() __builtin_amdgcn_s_barrier()
#define WAITV0()  asm volatile("s_waitcnt vmcnt(0)" ::: "memory")
#define WAITV4()  asm volatile("s_waitcnt vmcnt(4)" ::: "memory")

// cluster: 1 m-tile x 2 n-tiles x 4 k-steps = 8 MFMA, ks-outer (independent
// consecutive MFMAs — R13's verified +4%)
#define CL(AF, MT) do {                                                      \
    __builtin_amdgcn_s_setprio(1);                                           \
    _Pragma("unroll") for (int ks = 0; ks < 4; ++ks)                         \
    _Pragma("unroll") for (int nt = 0; nt < 2; ++nt)                         \
        acc[MT][nt] = __builtin_amdgcn_mfma_i32_32x32x32_i8(                 \
            AF[ks], bf[nt][ks], acc[MT][nt], 0, 0, 0);                       \
    __builtin_amdgcn_s_setprio(0);                                           \
} while (0)

// ---------------- prep kernels ----------------------------------------------

__global__ __launch_bounds__(256)
void quant_x_rowwise(const float* __restrict__ x, char* __restrict__ xq,
                     float* __restrict__ sx) {
    const int row = blockIdx.x;
    const float4* xr = reinterpret_cast<const float4*>(x + (size_t)row * Kdim);
    const int tid = threadIdx.x;
    float4 v[4];
    float am = 0.f;
    #pragma unroll
    for (int j = 0; j < 4; ++j) {
        v[j] = xr[tid + 256 * j];
        am = fmaxf(am, fmaxf(fmaxf(fabsf(v[j].x), fabsf(v[j].y)),
                             fmaxf(fabsf(v[j].z), fabsf(v[j].w))));
    }
    #pragma unroll
    for (int off = 32; off; off >>= 1)
        am = fmaxf(am, __shfl_xor(am, off, 64));
    __shared__ float red[4];
    if ((tid & 63) == 0) red[tid >> 6] = am;
    __syncthreads();
    am = fmaxf(fmaxf(red[0], red[1]), fmaxf(red[2], red[3]));
    am = fmaxf(am, 1e-30f);
    if (tid == 0) sx[row] = am / 127.f;
    const float inv = 127.f / am;
    int* outw = reinterpret_cast<int*>(xq + (size_t)row * Kdim);
    #pragma unroll
    for (int j = 0; j < 4; ++j) {
        const int q0 = (int)rintf(v[j].x * inv) & 255;
        const int q1 = (int)rintf(v[j].y * inv) & 255;
        const int q2 = (int)rintf(v[j].z * inv) & 255;
        const int q3 = (int)rintf(v[j].w * inv) & 255;
        outw[tid + 256 * j] = q0 | (q1 << 8) | (q2 << 16) | (q3 << 24);
    }
}

__global__ __launch_bounds__(256)
void pack_w_int8(const int* __restrict__ w, char* __restrict__ wq, int n4) {
    int idx = blockIdx.x * blockDim.x + threadIdx.x;
    const int stride = gridDim.x * blockDim.x;
    int* out = reinterpret_cast<int*>(wq);
    for (int i = idx; i < n4; i += stride) {
        const int4 a = reinterpret_cast<const int4*>(w)[i];
        out[i] = (a.x & 255) | ((a.y & 255) << 8) |
                 ((a.z & 255) << 16) | ((a.w & 255) << 24);
    }
}

// ---------------- 256x256 even-spread int8 GEMM -----------------------------

__global__ __launch_bounds__(512, 2)
void gemm_i8_spread(const char* __restrict__ A,   // [M][K] int8
                    const char* __restrict__ B,   // [N][K] int8
                    const float* __restrict__ scale,
                    const float* __restrict__ bias,
                    const float* __restrict__ sx,
                    float* __restrict__ Out)
{
    // [buf][half: A0,A1,B0,B1][16 KiB] = 128 KiB
    __shared__ __align__(16) char smem[2][4][16384];

    const int tid = threadIdx.x;
    int bid = blockIdx.x;
    bid = (bid & 7) * 64 + (bid >> 3);          // bijective XCD swizzle (512%8==0)
    const int tn = bid & 15;
    const int tm = bid >> 4;
    const int brow = tm * BM;
    const int bcol = tn * BN;

    const int lane = tid & 63;
    const int w    = tid >> 6;                  // 8 waves
    const int wr   = w >> 2;                    // 2 M-waves
    const int wc   = w & 3;                     // 4 N-waves
    const int r32  = lane & 31;
    const int h    = lane >> 5;
    const size_t K1 = (size_t)Kdim;

    // staging (two-level swizzle, zero-conflict r6-r13)
    const int swzb = ((lane & 7) ^ (lane >> 3) ^ (w & 3)) << 4;
    const char* aStageSrc = A + (size_t)(brow + w * 8 + (lane >> 3)) * K1 + swzb;
    const char* bStageSrc = B + (size_t)(bcol + w * 8 + (lane >> 3)) * K1 + swzb;

    auto stageA = [&](int bufb, int hh, int tt) {   // 2 gloads
        const char* s = aStageSrc + (size_t)(hh * 128) * K1 + (size_t)tt * BKB;
        char* d = &smem[bufb][hh][w * 1024];
        gload_lds16(s, d);
        gload_lds16(s + 64 * K1, d + 8192);
    };
    auto stageB = [&](int bufb, int hh, int tt) {
        const char* s = bStageSrc + (size_t)(hh * 128) * K1 + (size_t)tt * BKB;
        char* d = &smem[bufb][2 + hh][w * 1024];
        gload_lds16(s, d);
        gload_lds16(s + 64 * K1, d + 8192);
    };

    // ds_read bases
    const char* aB0 = &smem[0][wr][0] + r32 * 128;
    const char* aB1 = &smem[1][wr][0] + r32 * 128;
    const char* bB0 = &smem[0][2 + (wc >> 1)][0] + ((wc & 1) * 64 + r32) * 128;
    const char* bB1 = &smem[1][2 + (wc >> 1)][0] + ((wc & 1) * 64 + r32) * 128;
    const int frx = ((r32 & 7) ^ (r32 >> 3)) << 4;
    int colb[4];
    #pragma unroll
    for (int ks = 0; ks < 4; ++ks) colb[ks] = (ks * 32 + h * 16) ^ frx;

    int32x16 acc[4][2] = {};          // [m-tile][n-tile]
    int32x4 afA[4], afB[4], bf[2][4]; // af: 2 rotating slots

    auto ldAf = [&](int32x4* dst, const char* base, int mt) {  // 4 ds_reads
        #pragma unroll
        for (int ks = 0; ks < 4; ++ks)
            dst[ks] = *reinterpret_cast<const int32x4*>(base + mt * 4096 + colb[ks]);
    };
    auto ldBf = [&](const char* base) {                        // 8 ds_reads
        #pragma unroll
        for (int nt = 0; nt < 2; ++nt)
            #pragma unroll
            for (int ks = 0; ks < 4; ++ks)
                bf[nt][ks] = *reinterpret_cast<const int32x4*>(base + nt * 4096 + colb[ks]);
    };

    // ---- prologue: t0 full -> buf0 (8 ops), B0,B1(t1) -> buf1 (4 ops)
    stageB(0, 0, 0); stageB(0, 1, 0); stageA(0, 0, 0); stageA(0, 1, 0);
    stageB(1, 0, 1); stageB(1, 1, 1);
    WAITV4();          // drains t0; B(t1) may stay in flight
    BARRIER();
    ldAf(afA, aB0, 0);
    ldBf(bB0);

    // ---- main loop: 15 pairs, tiles 0..29 ----
    for (int i = 0; i < KT / 2 - 1; ++i) {
        const int te = 2 * i;
        // ======== even tile te (buf0); stage A(te+1)->buf1, B(te+2)->buf0
        // P0
        BARRIER();
        stageA(1, 0, te + 1);
        CL(afA, 0);
        ldAf(afB, aB0, 1);
        // P1
        BARRIER();
        stageA(1, 1, te + 1);
        stageB(0, 0, te + 2);
        CL(afB, 1);
        ldAf(afA, aB0, 2);
        // P2
        BARRIER();
        stageB(0, 1, te + 2);
        CL(afA, 2);
        ldAf(afB, aB0, 3);
        WAITV4();      // drains A(te+1) (+older); leaves B(te+2)
        // P3
        BARRIER();
        CL(afB, 3);
        ldAf(afA, aB1, 0);   // tile te+1 operands (buf1 complete)
        ldBf(bB1);           // after CL: WAR on bf regs by program order
        // ======== odd tile te+1 (buf1); stage A(te+2)->buf0, B(te+3)->buf1
        // P0
        BARRIER();
        stageA(0, 0, te + 2);
        CL(afA, 0);
        ldAf(afB, aB1, 1);
        // P1
        BARRIER();
        stageA(0, 1, te + 2);
        stageB(1, 0, te + 3);
        CL(afB, 1);
        ldAf(afA, aB1, 2);
        // P2
        BARRIER();
        stageB(1, 1, te + 3);
        CL(afA, 2);
        ldAf(afB, aB1, 3);
        WAITV4();      // drains A(te+2); leaves B(te+3)
        // P3
        BARRIER();
        CL(afB, 3);
        ldAf(afA, aB0, 0);   // tile te+2 operands (buf0 complete)
        ldBf(bB0);
    }

    // ---- tile 30 (buf0): stage A(31)->buf1 only; full drain at P2
    {
        BARRIER();
        stageA(1, 0, KT - 1);
        CL(afA, 0);
        ldAf(afB, aB0, 1);
        BARRIER();
        stageA(1, 1, KT - 1);
        CL(afB, 1);
        ldAf(afA, aB0, 2);
        BARRIER();
        CL(afA, 2);
        ldAf(afB, aB0, 3);
        WAITV0();      // no B-stages issued this tile: drain A(31) fully
        BARRIER();
        CL(afB, 3);
        ldAf(afA, aB1, 0);
        ldBf(bB1);
    }
    // ---- tile 31 (buf1): no stages, no next-tile reads
    {
        BARRIER();
        CL(afA, 0);
        ldAf(afB, aB1, 1);
        BARRIER();
        CL(afB, 1);
        ldAf(afA, aB1, 2);
        BARRIER();
        CL(afA, 2);
        ldAf(afB, aB1, 3);
        BARRIER();
        CL(afB, 3);
    }

    // epilogue: out = acc * scale[col] * scale_x[row] + bias[col]
    // C/D (32x32): col=lane&31, row=(reg&3)+8*(reg>>2)+4*(lane>>5)
    #pragma unroll
    for (int mt = 0; mt < 4; ++mt) {
        const int rb = brow + wr * 128 + mt * 32 + 4 * h;
        float sxr[4][4];
        #pragma unroll
        for (int q = 0; q < 4; ++q)
            #pragma unroll
            for (int r = 0; r < 4; ++r)
                sxr[q][r] = sx[rb + 8 * q + r];
        #pragma unroll
        for (int nt = 0; nt < 2; ++nt) {
            const int col = bcol + wc * 64 + nt * 32 + r32;
            const float sc = scale[col];
            const float bi = bias[col];
            #pragma unroll
            for (int q = 0; q < 4; ++q) {
                const int r4 = rb + 8 * q;
                #pragma unroll
                for (int r = 0; r < 4; ++r) {
                    Out[(size_t)(r4 + r) * Ndim + col] =
                        (float)acc[mt][nt][q * 4 + r] * (sc * sxr[q][r]) + bi;
                }
            }
        }
    }
}

// ---------------- fallback (round-1 kernel) if ws too small -----------------

__device__ __forceinline__ int swz_fb(int row, int colbyte) {
    return row * 128 + (colbyte ^ ((row & 7) << 4));
}

__global__ __launch_bounds__(256)
void compressed_linear_fb(const float* __restrict__ X,
                          const int*   __restrict__ W,
                          const float* __restrict__ scale,
                          const float* __restrict__ bias,
                          float* __restrict__ Out)
{
    __shared__ __align__(16) ushort_t lA[128 * 64];
    __shared__ __align__(16) ushort_t lB[128 * 64];
    const int tid = threadIdx.x;
    const int bid = blockIdx.x;
    const int tn = bid & 31, tm = bid >> 5;
    const int brow = tm * 128, bcol = tn * 128;
    const int r0 = tid >> 3, c0 = tid & 7;
    float4 aPre[4][2]; int4 bPre[4][2];
    const int lane = tid & 63, w = tid >> 6;
    const int wr = w >> 1, wc = w & 1, fr = lane & 15, fq = lane >> 4;
    f32x4 acc[4][4] = {};

    auto loadTiles = [&](int t) {
        const int k0 = t * 64;
        #pragma unroll
        for (int i = 0; i < 4; i++) {
            const int row = r0 + 32 * i;
            const float4* pa = reinterpret_cast<const float4*>(X + (size_t)(brow + row) * Kdim + k0 + c0 * 8);
            aPre[i][0] = pa[0]; aPre[i][1] = pa[1];
            const int4* pb = reinterpret_cast<const int4*>(W + (size_t)(bcol + row) * Kdim + k0 + c0 * 8);
            bPre[i][0] = pb[0]; bPre[i][1] = pb[1];
        }
    };
    auto writeLDS = [&]() {
        #pragma unroll
        for (int i = 0; i < 4; i++) {
            const int row = r0 + 32 * i;
            const int off = swz_fb(row, c0 * 16);
            short8 va, vb;
            va[0] = (short)f2bf(aPre[i][0].x); va[1] = (short)f2bf(aPre[i][0].y);
            va[2] = (short)f2bf(aPre[i][0].z); va[3] = (short)f2bf(aPre[i][0].w);
            va[4] = (short)f2bf(aPre[i][1].x); va[5] = (short)f2bf(aPre[i][1].y);
            va[6] = (short)f2bf(aPre[i][1].z); va[7] = (short)f2bf(aPre[i][1].w);
            vb[0] = (short)f2bf((float)bPre[i][0].x); vb[1] = (short)f2bf((float)bPre[i][0].y);
            vb[2] = (short)f2bf((float)bPre[i][0].z); vb[3] = (short)f2bf((float)bPre[i][0].w);
            vb[4] = (short)f2bf((float)bPre[i][1].x); vb[5] = (short)f2bf((float)bPre[i][1].y);
            vb[6] = (short)f2bf((float)bPre[i][1].z); vb[7] = (short)f2bf((float)bPre[i][1].w);
            *reinterpret_cast<short8*>(reinterpret_cast<char*>(lA) + off) = va;
            *reinterpret_cast<short8*>(reinterpret_cast<char*>(lB) + off) = vb;
        }
    };

    loadTiles(0);
    for (int t = 0; t < Kdim / 64; t++) {
        writeLDS();
        __syncthreads();
        if (t + 1 < Kdim / 64) loadTiles(t + 1);
        #pragma unroll
        for (int kk = 0; kk < 2; kk++) {
            short8 afv[4], bfv[4];
            const int cb = kk * 64 + fq * 16;
            #pragma unroll
            for (int m = 0; m < 4; m++) {
                const int row = wr * 64 + m * 16 + fr;
                afv[m] = *reinterpret_cast<const short8*>(reinterpret_cast<const char*>(lA) + swz_fb(row, cb));
            }
            #pragma unroll
            for (int n = 0; n < 4; n++) {
                const int row = wc * 64 + n * 16 + fr;
                bfv[n] = *reinterpret_cast<const short8*>(reinterpret_cast<const char*>(lB) + swz_fb(row, cb));
            }
            #pragma unroll
            for (int m = 0; m < 4; m++)
                #pragma unroll
                for (int n = 0; n < 4; n++)
                    acc[m][n] = __builtin_amdgcn_mfma_f32_16x16x32_bf16(afv[m], bfv[n], acc[m][n], 0, 0, 0);
        }
        __syncthreads();
    }
    #pragma unroll
    for (int n = 0; n < 4; n++) {
        const int col = bcol + wc * 64 + n * 16 + fr;
        const float sc = scale[col];
        const float bi = bias[col];
        #pragma unroll
        for (int m = 0; m < 4; m++) {
            const int rbase = brow + wr * 64 + m * 16 + fq * 4;
            #pragma unroll
            for (int j = 0; j < 4; j++)
                Out[(size_t)(rbase + j) * Ndim + col] = acc[m][n][j] * sc + bi;
        }
    }
}

// ---------------------------------------------------------------------------

extern "C" void kernel_launch(void* const* d_in, const int* in_sizes, int n_in,
                              void* d_out, int out_size, void* d_ws, size_t ws_size,
                              hipStream_t stream) {
    const float* x     = (const float*)d_in[0];
    const int*   w8    = (const int*)d_in[1];
    const float* scale = (const float*)d_in[2];
    const float* bias  = (const float*)d_in[3];
    float* out = (float*)d_out;

    const size_t xq_bytes = (size_t)Mdim * Kdim;        // 32 MiB
    const size_t wq_bytes = (size_t)Ndim * Kdim;        // 16 MiB
    const size_t sx_bytes = (size_t)Mdim * sizeof(float);

    if (ws_size >= xq_bytes + wq_bytes + sx_bytes) {
        char*  xq = (char*)d_ws;
        char*  wq = (char*)d_ws + xq_bytes;
        float* sx = (float*)((char*)d_ws + xq_bytes + wq_bytes);
        quant_x_rowwise<<<Mdim, 256, 0, stream>>>(x, xq, sx);
        pack_w_int8<<<2048, 256, 0, stream>>>(w8, wq, (Ndim * Kdim) / 4);
        dim3 grid((Mdim / BM) * (Ndim / BN));           // 512 blocks
        gemm_i8_spread<<<grid, dim3(512), 0, stream>>>(xq, wq, scale, bias, sx, out);
    } else {
        dim3 grid((Mdim / 128) * (Ndim / 128));
        compressed_linear_fb<<<grid, dim3(256), 0, stream>>>(x, w8, scale, bias, out);
    }
}

// Round 15
// 188.385 us; speedup vs baseline: 1.4572x; 1.0035x over previous
//
#include <hip/hip_runtime.h>

// CompressedLinear: out = x[8192,4096] @ (W_int8[4096,4096]*scale)^T + bias.
// Round 15: single-variable A/B vs R13 champion (140.6us). ONLY change: MFMA
// cluster partition (MH, NH) -> (MH, KS-pair), so each 8-MFMA cluster cycles
// ks x mt x nt with accumulator revisit distance 4 (was 2). Rationale: 32x32
// MFMAs are ~37-cyc ops; R13's distance-1->2 change gave +4% (signature of
// partially-covered acc RAW latency); distance 4 = ~146 cyc cover. Operand
// availability per phase is unchanged (g0 reads bf all-ks + af mt0-1 all-ks;
// g2 reads af mt2-3), so reads/stages/barriers/waits/registers are IDENTICAL
// to R13. Int32 accumulation is order-exact: absmax must stay 2.265625.

#define BM 256
#define BN 256
#define BKB 128                 // K-bytes per tile = 128 int8

constexpr int Mdim = 8192;
constexpr int Ndim = 4096;
constexpr int Kdim = 4096;
constexpr int KT = Kdim / BKB;  // 32

typedef __attribute__((ext_vector_type(4)))  int   int32x4;
typedef __attribute__((ext_vector_type(16))) int   int32x16;
typedef __attribute__((ext_vector_type(8)))  short short8;
typedef __attribute__((ext_vector_type(4)))  float f32x4;
typedef unsigned short ushort_t;

__device__ __forceinline__ unsigned short f2bf(float f) {
    union { float f; unsigned u; } v; v.f = f;
    unsigned r = v.u + 0x7FFFu + ((v.u >> 16) & 1u);
    return (unsigned short)(r >> 16);
}

__device__ __forceinline__ void gload_lds16(const void* g, void* l) {
    __builtin_amdgcn_global_load_lds(
        (const __attribute__((address_space(1))) void*)g,
        (__attribute__((address_space(3))) void*)l, 16, 0, 0);
}

#define BARRIER() __builtin_amdgcn_s_barrier()
#define LGKM0()   asm volatile("s_waitcnt lgkmcnt(0)" ::: "memory")
#define WAITV0()  asm volatile("s_waitcnt vmcnt(0)" ::: "memory")
#define WAITV6()  asm volatile("s_waitcnt vmcnt(6)" ::: "memory")

// one cluster: ks-pair (KSP) x 2 m-tiles x 2 n-tiles = 8 MFMA (i8 32x32x32).
// Iteration order ks-outer, (mt,nt) inner: acc[(MH)*2+mt][nt] revisited every
// 4 MFMAs (distance 4, ~146 cyc) — covers accumulator RAW latency.
#define MFMAQ(MH, KSP) do {                                                  \
    __builtin_amdgcn_s_setprio(1);                                           \
    _Pragma("unroll") for (int kf = 0; kf < 2; ++kf)                         \
    _Pragma("unroll") for (int mt = 0; mt < 2; ++mt)                         \
    _Pragma("unroll") for (int nt = 0; nt < 2; ++nt)                         \
        acc[(MH)*2+mt][nt] = __builtin_amdgcn_mfma_i32_32x32x32_i8(          \
            af[mt][(KSP)*2+kf], bf[nt][(KSP)*2+kf],                          \
            acc[(MH)*2+mt][nt], 0, 0, 0);                                    \
    __builtin_amdgcn_s_setprio(0);                                           \
} while (0)

// ---------------- prep kernels ----------------------------------------------

// per-row symmetric int8 quantization of x; one block per row
__global__ __launch_bounds__(256)
void quant_x_rowwise(const float* __restrict__ x, char* __restrict__ xq,
                     float* __restrict__ sx) {
    const int row = blockIdx.x;
    const float4* xr = reinterpret_cast<const float4*>(x + (size_t)row * Kdim);
    const int tid = threadIdx.x;
    float4 v[4];
    float am = 0.f;
    #pragma unroll
    for (int j = 0; j < 4; ++j) {
        v[j] = xr[tid + 256 * j];
        am = fmaxf(am, fmaxf(fmaxf(fabsf(v[j].x), fabsf(v[j].y)),
                             fmaxf(fabsf(v[j].z), fabsf(v[j].w))));
    }
    #pragma unroll
    for (int off = 32; off; off >>= 1)
        am = fmaxf(am, __shfl_xor(am, off, 64));
    __shared__ float red[4];
    if ((tid & 63) == 0) red[tid >> 6] = am;
    __syncthreads();
    am = fmaxf(fmaxf(red[0], red[1]), fmaxf(red[2], red[3]));
    am = fmaxf(am, 1e-30f);
    if (tid == 0) sx[row] = am / 127.f;
    const float inv = 127.f / am;
    int* outw = reinterpret_cast<int*>(xq + (size_t)row * Kdim);
    #pragma unroll
    for (int j = 0; j < 4; ++j) {
        const int q0 = (int)rintf(v[j].x * inv) & 255;
        const int q1 = (int)rintf(v[j].y * inv) & 255;
        const int q2 = (int)rintf(v[j].z * inv) & 255;
        const int q3 = (int)rintf(v[j].w * inv) & 255;
        outw[tid + 256 * j] = q0 | (q1 << 8) | (q2 << 16) | (q3 << 24);
    }
}

// pack W int32 (values in [-128,127]) -> int8
__global__ __launch_bounds__(256)
void pack_w_int8(const int* __restrict__ w, char* __restrict__ wq, int n4) {
    int idx = blockIdx.x * blockDim.x + threadIdx.x;
    const int stride = gridDim.x * blockDim.x;
    int* out = reinterpret_cast<int*>(wq);
    for (int i = idx; i < n4; i += stride) {
        const int4 a = reinterpret_cast<const int4*>(w)[i];
        out[i] = (a.x & 255) | ((a.y & 255) << 8) |
                 ((a.z & 255) << 16) | ((a.w & 255) << 24);
    }
}

// ---------------- 256x256 8-phase int8 GEMM ---------------------------------

__global__ __launch_bounds__(512, 2)
void gemm_i8_8phase(const char* __restrict__ A,   // [M][K] int8
                    const char* __restrict__ B,   // [N][K] int8
                    const float* __restrict__ scale,
                    const float* __restrict__ bias,
                    const float* __restrict__ sx,
                    float* __restrict__ Out)
{
    // [buf][half: A0,A1,B0,B1][16 KiB] = 128 KiB
    __shared__ __align__(16) char smem[2][4][16384];

    const int tid = threadIdx.x;
    int bid = blockIdx.x;
    bid = (bid & 7) * 64 + (bid >> 3);          // bijective XCD swizzle (512%8==0)
    const int tn = bid & 15;                    // N/BN = 16
    const int tm = bid >> 4;                    // M/BM = 32
    const int brow = tm * BM;
    const int bcol = tn * BN;

    const int lane = tid & 63;
    const int w    = tid >> 6;                  // 8 waves
    const int wr   = w >> 2;                    // 2 M-waves
    const int wc   = w & 3;                     // 4 N-waves
    const int r32  = lane & 31;
    const int h    = lane >> 5;                 // k-group
    const size_t K1 = (size_t)Kdim;             // row stride in bytes (int8)

    // staging source (pre-swizzled global address; LDS dest stays linear)
    // two-level swizzle nibble = (l&7) ^ (row&7) ^ ((row>>3)&3)
    const int swzb = ((lane & 7) ^ (lane >> 3) ^ (w & 3)) << 4;
    const char* aStageSrc = A + (size_t)(brow + w * 8 + (lane >> 3)) * K1 + swzb;
    const char* bStageSrc = B + (size_t)(bcol + w * 8 + (lane >> 3)) * K1 + swzb;

    auto stageA = [&](int bufb, int hh, int tt) {
        const char* s = aStageSrc + (size_t)(hh * 128) * K1 + (size_t)tt * BKB;
        char* d = &smem[bufb][hh][w * 1024];
        gload_lds16(s, d);
        gload_lds16(s + 64 * K1, d + 8192);
    };
    auto stageB = [&](int bufb, int hh, int tt) {
        const char* s = bStageSrc + (size_t)(hh * 128) * K1 + (size_t)tt * BKB;
        char* d = &smem[bufb][2 + hh][w * 1024];
        gload_lds16(s, d);
        gload_lds16(s + 64 * K1, d + 8192);
    };

    // ds_read bases (row stride 128B; proven zero-conflict geometry)
    const char* aBase[2] = { &smem[0][wr][0] + r32 * 128,
                             &smem[1][wr][0] + r32 * 128 };
    const char* bBase[2] = { &smem[0][2 + (wc >> 1)][0] + ((wc & 1) * 64 + r32) * 128,
                             &smem[1][2 + (wc >> 1)][0] + ((wc & 1) * 64 + r32) * 128 };
    const int frx = ((r32 & 7) ^ (r32 >> 3)) << 4;
    int colb[4];
    #pragma unroll
    for (int ks = 0; ks < 4; ++ks) colb[ks] = (ks * 32 + h * 16) ^ frx;

    int32x16 acc[4][2] = {};     // [m-tile][n-tile]
    int32x4 af[2][4], bf[2][4];  // [tile][k-step], 16 int8 each

    auto ldA = [&](const char* base, int MH) {
        #pragma unroll
        for (int mt = 0; mt < 2; ++mt) {
            const char* p = base + ((MH) * 2 + mt) * 4096;   // 32 rows * 128B
            #pragma unroll
            for (int ks = 0; ks < 4; ++ks)
                af[mt][ks] = *reinterpret_cast<const int32x4*>(p + colb[ks]);
        }
    };
    auto ldB = [&](const char* base) {
        #pragma unroll
        for (int nt = 0; nt < 2; ++nt) {
            const char* p = base + nt * 4096;
            #pragma unroll
            for (int ks = 0; ks < 4; ++ks)
                bf[nt][ks] = *reinterpret_cast<const int32x4*>(p + colb[ks]);
        }
    };

    // ---- prologue: t0 full + t1 {B0,B1,A0}; t1's 3 halves may stay in flight
    stageB(0, 0, 0); stageB(0, 1, 0); stageA(0, 0, 0); stageA(0, 1, 0);
    stageB(1, 0, 1); stageB(1, 1, 1); stageA(1, 0, 1);
    WAITV6();          // oldest 8 ops (= all of t0/buf0) landed
    BARRIER();

    // ---- main loop: 15 iterations, all stages unconditional ----
    for (int i = 0; i < KT / 2 - 1; ++i) {
        const int t = 2 * i;

        // g0: mt0-1 x ks0-1 of t (buf0)
        ldB(bBase[0]); ldA(aBase[0], 0);
        stageA(1, 1, t + 1);
        BARRIER(); LGKM0();
        MFMAQ(0, 0);
        BARRIER();
        // g1: mt0-1 x ks2-3
        stageB(0, 0, t + 2);
        BARRIER(); LGKM0();
        MFMAQ(0, 1);
        BARRIER();
        // g2: mt2-3 x ks0-1
        ldA(aBase[0], 1);
        stageB(0, 1, t + 2);
        BARRIER(); LGKM0();
        MFMAQ(1, 0);
        BARRIER();
        // g3: mt2-3 x ks2-3 (+ K-tile wait: buf1/t+1 landed)
        stageA(0, 0, t + 2);
        BARRIER(); LGKM0();
        MFMAQ(1, 1);
        WAITV6();
        BARRIER();
        // g4: mt0-1 x ks0-1 of t+1 (buf1)
        ldB(bBase[1]); ldA(aBase[1], 0);
        stageA(0, 1, t + 2);
        BARRIER(); LGKM0();
        MFMAQ(0, 0);
        BARRIER();
        // g5
        stageB(1, 0, t + 3);
        BARRIER(); LGKM0();
        MFMAQ(0, 1);
        BARRIER();
        // g6
        ldA(aBase[1], 1);
        stageB(1, 1, t + 3);
        BARRIER(); LGKM0();
        MFMAQ(1, 0);
        BARRIER();
        // g7 (+ K-tile wait: buf0/t+2 landed)
        stageA(1, 0, t + 3);
        BARRIER(); LGKM0();
        MFMAQ(1, 1);
        WAITV6();
        BARRIER();
    }

    // ---- peeled tail: t = KT-2; only remaining stage is (buf1.A1, KT-1).
    //      Full drain at g3 so buf1/t+1 is guaranteed landed before g4/g6.
    {
        // g0
        ldB(bBase[0]); ldA(aBase[0], 0);
        stageA(1, 1, KT - 1);
        BARRIER(); LGKM0();
        MFMAQ(0, 0);
        BARRIER();
        // g1
        MFMAQ(0, 1);
        BARRIER();
        // g2
        ldA(aBase[0], 1);
        BARRIER(); LGKM0();
        MFMAQ(1, 0);
        BARRIER();
        // g3: drain everything
        MFMAQ(1, 1);
        WAITV0();
        BARRIER();
        // g4
        ldB(bBase[1]); ldA(aBase[1], 0);
        BARRIER(); LGKM0();
        MFMAQ(0, 0);
        // g5
        MFMAQ(0, 1);
        // g6
        ldA(aBase[1], 1);
        LGKM0();
        MFMAQ(1, 0);
        // g7
        MFMAQ(1, 1);
    }

    // epilogue: out = acc * scale[col] * scale_x[row] + bias[col]
    // C/D (32x32): col=lane&31, row=(reg&3)+8*(reg>>2)+4*(lane>>5)
    #pragma unroll
    for (int mt = 0; mt < 4; ++mt) {
        const int rb = brow + wr * 128 + mt * 32 + 4 * h;
        float sxr[4][4];
        #pragma unroll
        for (int q = 0; q < 4; ++q)
            #pragma unroll
            for (int r = 0; r < 4; ++r)
                sxr[q][r] = sx[rb + 8 * q + r];
        #pragma unroll
        for (int nt = 0; nt < 2; ++nt) {
            const int col = bcol + wc * 64 + nt * 32 + r32;
            const float sc = scale[col];
            const float bi = bias[col];
            #pragma unroll
            for (int q = 0; q < 4; ++q) {
                const int r4 = rb + 8 * q;
                #pragma unroll
                for (int r = 0; r < 4; ++r) {
                    Out[(size_t)(r4 + r) * Ndim + col] =
                        (float)acc[mt][nt][q * 4 + r] * (sc * sxr[q][r]) + bi;
                }
            }
        }
    }
}

// ---------------- fallback (round-1 kernel) if ws too small -----------------

__device__ __forceinline__ int swz_fb(int row, int colbyte) {
    return row * 128 + (colbyte ^ ((row & 7) << 4));
}

__global__ __launch_bounds__(256)
void compressed_linear_fb(const float* __restrict__ X,
                          const int*   __restrict__ W,
                          const float* __restrict__ scale,
                          const float* __restrict__ bias,
                          float* __restrict__ Out)
{
    __shared__ __align__(16) ushort_t lA[128 * 64];
    __shared__ __align__(16) ushort_t lB[128 * 64];
    const int tid = threadIdx.x;
    const int bid = blockIdx.x;
    const int tn = bid & 31, tm = bid >> 5;
    const int brow = tm * 128, bcol = tn * 128;
    const int r0 = tid >> 3, c0 = tid & 7;
    float4 aPre[4][2]; int4 bPre[4][2];
    const int lane = tid & 63, w = tid >> 6;
    const int wr = w >> 1, wc = w & 1, fr = lane & 15, fq = lane >> 4;
    f32x4 acc[4][4] = {};

    auto loadTiles = [&](int t) {
        const int k0 = t * 64;
        #pragma unroll
        for (int i = 0; i < 4; i++) {
            const int row = r0 + 32 * i;
            const float4* pa = reinterpret_cast<const float4*>(X + (size_t)(brow + row) * Kdim + k0 + c0 * 8);
            aPre[i][0] = pa[0]; aPre[i][1] = pa[1];
            const int4* pb = reinterpret_cast<const int4*>(W + (size_t)(bcol + row) * Kdim + k0 + c0 * 8);
            bPre[i][0] = pb[0]; bPre[i][1] = pb[1];
        }
    };
    auto writeLDS = [&]() {
        #pragma unroll
        for (int i = 0; i < 4; i++) {
            const int row = r0 + 32 * i;
            const int off = swz_fb(row, c0 * 16);
            short8 va, vb;
            va[0] = (short)f2bf(aPre[i][0].x); va[1] = (short)f2bf(aPre[i][0].y);
            va[2] = (short)f2bf(aPre[i][0].z); va[3] = (short)f2bf(aPre[i][0].w);
            va[4] = (short)f2bf(aPre[i][1].x); va[5] = (short)f2bf(aPre[i][1].y);
            va[6] = (short)f2bf(aPre[i][1].z); va[7] = (short)f2bf(aPre[i][1].w);
            vb[0] = (short)f2bf((float)bPre[i][0].x); vb[1] = (short)f2bf((float)bPre[i][0].y);
            vb[2] = (short)f2bf((float)bPre[i][0].z); vb[3] = (short)f2bf((float)bPre[i][0].w);
            vb[4] = (short)f2bf((float)bPre[i][1].x); vb[5] = (short)f2bf((float)bPre[i][1].y);
            vb[6] = (short)f2bf((float)bPre[i][1].z); vb[7] = (short)f2bf((float)bPre[i][1].w);
            *reinterpret_cast<short8*>(reinterpret_cast<char*>(lA) + off) = va;
            *reinterpret_cast<short8*>(reinterpret_cast<char*>(lB) + off) = vb;
        }
    };

    loadTiles(0);
    for (int t = 0; t < Kdim / 64; t++) {
        writeLDS();
        __syncthreads();
        if (t + 1 < Kdim / 64) loadTiles(t + 1);
        #pragma unroll
        for (int kk = 0; kk < 2; kk++) {
            short8 afv[4], bfv[4];
            const int cb = kk * 64 + fq * 16;
            #pragma unroll
            for (int m = 0; m < 4; m++) {
                const int row = wr * 64 + m * 16 + fr;
                afv[m] = *reinterpret_cast<const short8*>(reinterpret_cast<const char*>(lA) + swz_fb(row, cb));
            }
            #pragma unroll
            for (int n = 0; n < 4; n++) {
                const int row = wc * 64 + n * 16 + fr;
                bfv[n] = *reinterpret_cast<const short8*>(reinterpret_cast<const char*>(lB) + swz_fb(row, cb));
            }
            #pragma unroll
            for (int m = 0; m < 4; m++)
                #pragma unroll
                for (int n = 0; n < 4; n++)
                    acc[m][n] = __builtin_amdgcn_mfma_f32_16x16x32_bf16(afv[m], bfv[n], acc[m][n], 0, 0, 0);
        }
        __syncthreads();
    }
    #pragma unroll
    for (int n = 0; n < 4; n++) {
        const int col = bcol + wc * 64 + n * 16 + fr;
        const float sc = scale[col];
        const float bi = bias[col];
        #pragma unroll
        for (int m = 0; m < 4; m++) {
            const int rbase = brow + wr * 64 + m * 16 + fq * 4;
            #pragma unroll
            for (int j = 0; j < 4; j++)
                Out[(size_t)(rbase + j) * Ndim + col] = acc[m][n][j] * sc + bi;
        }
    }
}

// ---------------------------------------------------------------------------

extern "C" void kernel_launch(void* const* d_in, const int* in_sizes, int n_in,
                              void* d_out, int out_size, void* d_ws, size_t ws_size,
                              hipStream_t stream) {
    const float* x     = (const float*)d_in[0];
    const int*   w8    = (const int*)d_in[1];
    const float* scale = (const float*)d_in[2];
    const float* bias  = (const float*)d_in[3];
    float* out = (float*)d_out;

    const size_t xq_bytes = (size_t)Mdim * Kdim;        // 32 MiB
    const size_t wq_bytes = (size_t)Ndim * Kdim;        // 16 MiB
    const size_t sx_bytes = (size_t)Mdim * sizeof(float);

    if (ws_size >= xq_bytes + wq_bytes + sx_bytes) {
        char*  xq = (char*)d_ws;
        char*  wq = (char*)d_ws + xq_bytes;
        float* sx = (float*)((char*)d_ws + xq_bytes + wq_bytes);
        quant_x_rowwise<<<Mdim, 256, 0, stream>>>(x, xq, sx);
        pack_w_int8<<<2048, 256, 0, stream>>>(w8, wq, (Ndim * Kdim) / 4);
        dim3 grid((Mdim / BM) * (Ndim / BN));           // 32*16 = 512 blocks
        gemm_i8_8phase<<<grid, dim3(512), 0, stream>>>(xq, wq, scale, bias, sx, out);
    } else {
        dim3 grid((Mdim / 128) * (Ndim / 128));         // 2048 blocks
        compressed_linear_fb<<<grid, dim3(256), 0, stream>>>(x, w8, scale, bias, out);
    }
}

// Round 16
// 188.197 us; speedup vs baseline: 1.4587x; 1.0010x over previous
//
#include <hip/hip_runtime.h>

// CompressedLinear: out = x[8192,4096] @ (W_int8[4096,4096]*scale)^T + bias.
// Round 16: break the 2-waves/SIMD register ceiling. All R7-R15 variants had
// acc 128 AGPR + ~124 VGPR ~ 252/wave -> 2 lockstep waves/SIMD -> LDS-port,
// MFMA and sync serialize (measured 1318 cyc/phase-pair = 586+350+380).
// New cut: 256x256 tile over 16 waves (1024 thr, 4x4 grid) -> acc/wave =
// 64x64 = 4 x int32x16 = 64 regs; total ~120 < 128 -> 4 waves/SIMD.
// Schedule: stage FULL next tile at tile start (safe: target buf consumed
// >=1 barrier ago), reads+MFMA flow per-wave (compiler partial lgkm),
// ONE WAITV0+barrier per K-tile (32 barriers vs 256). Same 512-block grid,
// same proven swizzle ((row>>3)&3 invariants re-verified for 4x4 decomp).
// Int32 accum exact -> absmax must stay 2.265625.

#define BM 256
#define BN 256
#define BKB 128                 // K-bytes per tile = 128 int8

constexpr int Mdim = 8192;
constexpr int Ndim = 4096;
constexpr int Kdim = 4096;
constexpr int KT = Kdim / BKB;  // 32

typedef __attribute__((ext_vector_type(4)))  int   int32x4;
typedef __attribute__((ext_vector_type(16))) int   int32x16;
typedef __attribute__((ext_vector_type(8)))  short short8;
typedef __attribute__((ext_vector_type(4)))  float f32x4;
typedef unsigned short ushort_t;

__device__ __forceinline__ unsigned short f2bf(float f) {
    union { float f; unsigned u; } v; v.f = f;
    unsigned r = v.u + 0x7FFFu + ((v.u >> 16) & 1u);
    return (unsigned short)(r >> 16);
}

__device__ __forceinline__ void gload_lds16(const void* g, void* l) {
    __builtin_amdgcn_global_load_lds(
        (const __attribute__((address_space(1))) void*)g,
        (__attribute__((address_space(3))) void*)l, 16, 0, 0);
}

#define BARRIER() __builtin_amdgcn_s_barrier()
#define WAITV0()  asm volatile("s_waitcnt vmcnt(0)" ::: "memory")

// ---------------- prep kernels ----------------------------------------------

__global__ __launch_bounds__(256)
void quant_x_rowwise(const float* __restrict__ x, char* __restrict__ xq,
                     float* __restrict__ sx) {
    const int row = blockIdx.x;
    const float4* xr = reinterpret_cast<const float4*>(x + (size_t)row * Kdim);
    const int tid = threadIdx.x;
    float4 v[4];
    float am = 0.f;
    #pragma unroll
    for (int j = 0; j < 4; ++j) {
        v[j] = xr[tid + 256 * j];
        am = fmaxf(am, fmaxf(fmaxf(fabsf(v[j].x), fabsf(v[j].y)),
                             fmaxf(fabsf(v[j].z), fabsf(v[j].w))));
    }
    #pragma unroll
    for (int off = 32; off; off >>= 1)
        am = fmaxf(am, __shfl_xor(am, off, 64));
    __shared__ float red[4];
    if ((tid & 63) == 0) red[tid >> 6] = am;
    __syncthreads();
    am = fmaxf(fmaxf(red[0], red[1]), fmaxf(red[2], red[3]));
    am = fmaxf(am, 1e-30f);
    if (tid == 0) sx[row] = am / 127.f;
    const float inv = 127.f / am;
    int* outw = reinterpret_cast<int*>(xq + (size_t)row * Kdim);
    #pragma unroll
    for (int j = 0; j < 4; ++j) {
        const int q0 = (int)rintf(v[j].x * inv) & 255;
        const int q1 = (int)rintf(v[j].y * inv) & 255;
        const int q2 = (int)rintf(v[j].z * inv) & 255;
        const int q3 = (int)rintf(v[j].w * inv) & 255;
        outw[tid + 256 * j] = q0 | (q1 << 8) | (q2 << 16) | (q3 << 24);
    }
}

__global__ __launch_bounds__(256)
void pack_w_int8(const int* __restrict__ w, char* __restrict__ wq, int n4) {
    int idx = blockIdx.x * blockDim.x + threadIdx.x;
    const int stride = gridDim.x * blockDim.x;
    int* out = reinterpret_cast<int*>(wq);
    for (int i = idx; i < n4; i += stride) {
        const int4 a = reinterpret_cast<const int4*>(w)[i];
        out[i] = (a.x & 255) | ((a.y & 255) << 8) |
                 ((a.z & 255) << 16) | ((a.w & 255) << 24);
    }
}

// ---------------- 256x256 16-wave int8 GEMM ---------------------------------

__global__ __launch_bounds__(1024)
void gemm_i8_16w(const char* __restrict__ A,   // [M][K] int8
                 const char* __restrict__ B,   // [N][K] int8
                 const float* __restrict__ scale,
                 const float* __restrict__ bias,
                 const float* __restrict__ sx,
                 float* __restrict__ Out)
{
    // [buf][region: A rows0-127, A rows128-255, B0, B1][16 KiB] = 128 KiB
    __shared__ __align__(16) char smem[2][4][16384];

    const int tid = threadIdx.x;
    int bid = blockIdx.x;
    bid = (bid & 7) * 64 + (bid >> 3);          // bijective XCD swizzle (512%8==0)
    const int tn = bid & 15;                    // N/BN = 16
    const int tm = bid >> 4;                    // M/BM = 32
    const int brow = tm * BM;
    const int bcol = tn * BN;

    const int lane = tid & 63;
    const int w    = tid >> 6;                  // 16 waves
    const int wr   = w >> 2;                    // 4 M-waves
    const int wc   = w & 3;                     // 4 N-waves
    const int r32  = lane & 31;
    const int h    = lane >> 5;
    const size_t K1 = (size_t)Kdim;

    // staging (two-level swizzle; invariants: row = hh*128 + w*8 + (lane>>3)
    // gives row&7 = lane>>3 and (row>>3)&3 = w&3 for all hh)
    const int swzb = ((lane & 7) ^ (lane >> 3) ^ (w & 3)) << 4;
    const char* aStageSrc = A + (size_t)(brow + w * 8 + (lane >> 3)) * K1 + swzb;
    const char* bStageSrc = B + (size_t)(bcol + w * 8 + (lane >> 3)) * K1 + swzb;

    // stage the FULL tile tt into buf b: 4 gloads/wave (1 KiB each)
    auto stageTile = [&](int b, int tt) {
        const size_t ko = (size_t)tt * BKB;
        #pragma unroll
        for (int hh = 0; hh < 2; ++hh)
            gload_lds16(aStageSrc + (size_t)(hh * 128) * K1 + ko,
                        &smem[b][hh][w * 1024]);
        #pragma unroll
        for (int hh = 0; hh < 2; ++hh)
            gload_lds16(bStageSrc + (size_t)(hh * 128) * K1 + ko,
                        &smem[b][2 + hh][w * 1024]);
    };

    // ds_read bases: wave owns A rows [wr*64, wr*64+64), B rows [wc*64, ...)
    const char* aBase[2] = {
        &smem[0][wr >> 1][0] + (((wr & 1) * 64) + r32) * 128,
        &smem[1][wr >> 1][0] + (((wr & 1) * 64) + r32) * 128 };
    const char* bBase[2] = {
        &smem[0][2 + (wc >> 1)][0] + (((wc & 1) * 64) + r32) * 128,
        &smem[1][2 + (wc >> 1)][0] + (((wc & 1) * 64) + r32) * 128 };
    const int frx = ((r32 & 7) ^ (r32 >> 3)) << 4;
    int colb[4];
    #pragma unroll
    for (int ks = 0; ks < 4; ++ks) colb[ks] = (ks * 32 + h * 16) ^ frx;

    int32x16 acc[2][2] = {};     // [mt][nt] — 64 regs
    int32x4 af[2][2], bf[2][2];  // [mt|nt][kf] — reused across ks-pairs

    auto ldA = [&](int buf, int ksp) {
        #pragma unroll
        for (int mt = 0; mt < 2; ++mt)
            #pragma unroll
            for (int kf = 0; kf < 2; ++kf)
                af[mt][kf] = *reinterpret_cast<const int32x4*>(
                    aBase[buf] + mt * 4096 + colb[ksp * 2 + kf]);
    };
    auto ldB = [&](int buf, int ksp) {
        #pragma unroll
        for (int nt = 0; nt < 2; ++nt)
            #pragma unroll
            for (int kf = 0; kf < 2; ++kf)
                bf[nt][kf] = *reinterpret_cast<const int32x4*>(
                    bBase[buf] + nt * 4096 + colb[ksp * 2 + kf]);
    };

    // half-tile MFMA: 2kf x 2mt x 2nt = 8 MFMA, acc revisit distance 4
    auto MFMAH = [&]() {
        __builtin_amdgcn_s_setprio(1);
        #pragma unroll
        for (int kf = 0; kf < 2; ++kf)
            #pragma unroll
            for (int mt = 0; mt < 2; ++mt)
                #pragma unroll
                for (int nt = 0; nt < 2; ++nt)
                    acc[mt][nt] = __builtin_amdgcn_mfma_i32_32x32x32_i8(
                        af[mt][kf], bf[nt][kf], acc[mt][nt], 0, 0, 0);
        __builtin_amdgcn_s_setprio(0);
    };

    // ---- prologue: stage t0 -> buf0, drain, publish
    stageTile(0, 0);
    WAITV0();
    BARRIER();

    // ---- main loop: tiles 0..30 stage t+1; one WAITV0+BARRIER per tile ----
    for (int t = 0; t < KT - 1; ++t) {
        const int c = t & 1;
        // issue next-tile stage early (lands under this tile's reads+MFMA)
        stageTile(1 - c, t + 1);
        // half 1 (ks 0-1)
        ldA(c, 0); ldB(c, 0);
        MFMAH();
        // half 2 (ks 2-3)
        ldA(c, 1); ldB(c, 1);
        MFMAH();
        WAITV0();      // stage issued ~700 cyc ago: mostly covered
        BARRIER();     // publish buf(1-c) for tile t+1
    }
    // ---- tile 31 (buf1): no stage, no sync
    {
        ldA(1, 0); ldB(1, 0);
        MFMAH();
        ldA(1, 1); ldB(1, 1);
        MFMAH();
    }

    // epilogue: out = acc * scale[col] * scale_x[row] + bias[col]
    // C/D (32x32): col=lane&31, row=(reg&3)+8*(reg>>2)+4*(lane>>5)
    #pragma unroll
    for (int mt = 0; mt < 2; ++mt) {
        const int rb = brow + wr * 64 + mt * 32 + 4 * h;
        float sxr[4][4];
        #pragma unroll
        for (int q = 0; q < 4; ++q)
            #pragma unroll
            for (int r = 0; r < 4; ++r)
                sxr[q][r] = sx[rb + 8 * q + r];
        #pragma unroll
        for (int nt = 0; nt < 2; ++nt) {
            const int col = bcol + wc * 64 + nt * 32 + r32;
            const float sc = scale[col];
            const float bi = bias[col];
            #pragma unroll
            for (int q = 0; q < 4; ++q) {
                const int r4 = rb + 8 * q;
                #pragma unroll
                for (int r = 0; r < 4; ++r) {
                    Out[(size_t)(r4 + r) * Ndim + col] =
                        (float)acc[mt][nt][q * 4 + r] * (sc * sxr[q][r]) + bi;
                }
            }
        }
    }
}

// ---------------- fallback (round-1 kernel) if ws too small -----------------

__device__ __forceinline__ int swz_fb(int row, int colbyte) {
    return row * 128 + (colbyte ^ ((row & 7) << 4));
}

__global__ __launch_bounds__(256)
void compressed_linear_fb(const float* __restrict__ X,
                          const int*   __restrict__ W,
                          const float* __restrict__ scale,
                          const float* __restrict__ bias,
                          float* __restrict__ Out)
{
    __shared__ __align__(16) ushort_t lA[128 * 64];
    __shared__ __align__(16) ushort_t lB[128 * 64];
    const int tid = threadIdx.x;
    const int bid = blockIdx.x;
    const int tn = bid & 31, tm = bid >> 5;
    const int brow = tm * 128, bcol = tn * 128;
    const int r0 = tid >> 3, c0 = tid & 7;
    float4 aPre[4][2]; int4 bPre[4][2];
    const int lane = tid & 63, w = tid >> 6;
    const int wr = w >> 1, wc = w & 1, fr = lane & 15, fq = lane >> 4;
    f32x4 acc[4][4] = {};

    auto loadTiles = [&](int t) {
        const int k0 = t * 64;
        #pragma unroll
        for (int i = 0; i < 4; i++) {
            const int row = r0 + 32 * i;
            const float4* pa = reinterpret_cast<const float4*>(X + (size_t)(brow + row) * Kdim + k0 + c0 * 8);
            aPre[i][0] = pa[0]; aPre[i][1] = pa[1];
            const int4* pb = reinterpret_cast<const int4*>(W + (size_t)(bcol + row) * Kdim + k0 + c0 * 8);
            bPre[i][0] = pb[0]; bPre[i][1] = pb[1];
        }
    };
    auto writeLDS = [&]() {
        #pragma unroll
        for (int i = 0; i < 4; i++) {
            const int row = r0 + 32 * i;
            const int off = swz_fb(row, c0 * 16);
            short8 va, vb;
            va[0] = (short)f2bf(aPre[i][0].x); va[1] = (short)f2bf(aPre[i][0].y);
            va[2] = (short)f2bf(aPre[i][0].z); va[3] = (short)f2bf(aPre[i][0].w);
            va[4] = (short)f2bf(aPre[i][1].x); va[5] = (short)f2bf(aPre[i][1].y);
            va[6] = (short)f2bf(aPre[i][1].z); va[7] = (short)f2bf(aPre[i][1].w);
            vb[0] = (short)f2bf((float)bPre[i][0].x); vb[1] = (short)f2bf((float)bPre[i][0].y);
            vb[2] = (short)f2bf((float)bPre[i][0].z); vb[3] = (short)f2bf((float)bPre[i][0].w);
            vb[4] = (short)f2bf((float)bPre[i][1].x); vb[5] = (short)f2bf((float)bPre[i][1].y);
            vb[6] = (short)f2bf((float)bPre[i][1].z); vb[7] = (short)f2bf((float)bPre[i][1].w);
            *reinterpret_cast<short8*>(reinterpret_cast<char*>(lA) + off) = va;
            *reinterpret_cast<short8*>(reinterpret_cast<char*>(lB) + off) = vb;
        }
    };

    loadTiles(0);
    for (int t = 0; t < Kdim / 64; t++) {
        writeLDS();
        __syncthreads();
        if (t + 1 < Kdim / 64) loadTiles(t + 1);
        #pragma unroll
        for (int kk = 0; kk < 2; kk++) {
            short8 afv[4], bfv[4];
            const int cb = kk * 64 + fq * 16;
            #pragma unroll
            for (int m = 0; m < 4; m++) {
                const int row = wr * 64 + m * 16 + fr;
                afv[m] = *reinterpret_cast<const short8*>(reinterpret_cast<const char*>(lA) + swz_fb(row, cb));
            }
            #pragma unroll
            for (int n = 0; n < 4; n++) {
                const int row = wc * 64 + n * 16 + fr;
                bfv[n] = *reinterpret_cast<const short8*>(reinterpret_cast<const char*>(lB) + swz_fb(row, cb));
            }
            #pragma unroll
            for (int m = 0; m < 4; m++)
                #pragma unroll
                for (int n = 0; n < 4; n++)
                    acc[m][n] = __builtin_amdgcn_mfma_f32_16x16x32_bf16(afv[m], bfv[n], acc[m][n], 0, 0, 0);
        }
        __syncthreads();
    }
    #pragma unroll
    for (int n = 0; n < 4; n++) {
        const int col = bcol + wc * 64 + n * 16 + fr;
        const float sc = scale[col];
        const float bi = bias[col];
        #pragma unroll
        for (int m = 0; m < 4; m++) {
            const int rbase = brow + wr * 64 + m * 16 + fq * 4;
            #pragma unroll
            for (int j = 0; j < 4; j++)
                Out[(size_t)(rbase + j) * Ndim + col] = acc[m][n][j] * sc + bi;
        }
    }
}

// ---------------------------------------------------------------------------

extern "C" void kernel_launch(void* const* d_in, const int* in_sizes, int n_in,
                              void* d_out, int out_size, void* d_ws, size_t ws_size,
                              hipStream_t stream) {
    const float* x     = (const float*)d_in[0];
    const int*   w8    = (const int*)d_in[1];
    const float* scale = (const float*)d_in[2];
    const float* bias  = (const float*)d_in[3];
    float* out = (float*)d_out;

    const size_t xq_bytes = (size_t)Mdim * Kdim;        // 32 MiB
    const size_t wq_bytes = (size_t)Ndim * Kdim;        // 16 MiB
    const size_t sx_bytes = (size_t)Mdim * sizeof(float);

    if (ws_size >= xq_bytes + wq_bytes + sx_bytes) {
        char*  xq = (char*)d_ws;
        char*  wq = (char*)d_ws + xq_bytes;
        float* sx = (float*)((char*)d_ws + xq_bytes + wq_bytes);
        quant_x_rowwise<<<Mdim, 256, 0, stream>>>(x, xq, sx);
        pack_w_int8<<<2048, 256, 0, stream>>>(w8, wq, (Ndim * Kdim) / 4);
        dim3 grid((Mdim / BM) * (Ndim / BN));           // 512 blocks
        gemm_i8_16w<<<grid, dim3(1024), 0, stream>>>(xq, wq, scale, bias, sx, out);
    } else {
        dim3 grid((Mdim / 128) * (Ndim / 128));
        compressed_linear_fb<<<grid, dim3(256), 0, stream>>>(x, w8, scale, bias, out);
    }
}